// Round 1
// baseline (11645.694 us; speedup 1.0000x reference)
//
#include <hip/hip_runtime.h>
#include <math.h>

// TransformerXL forward, fp32 reference-faithful baseline.
// Layout convention: all [t,b,*] tensors flattened with m = t*B_ + b.
// Workspace usage: ~80 MB (h 8MB, heads 24MB, pos 4MB, rk 4MB, avec 8MB, tmp 32MB).

#define T_   2048
#define B_   2
#define DM   512
#define NH   8
#define DH   64
#define DI   2048
#define INCH 2048
#define NCLS 64
#define MT   4096   // T_*B_

// ---------------------------------------------------------------- pos emb
__global__ __launch_bounds__(256) void pos_kernel(float* __restrict__ pe) {
  int idx = blockIdx.x * 256 + threadIdx.x;
  if (idx >= T_ * DM) return;
  int t = idx >> 9;         // row
  int i = idx & 511;        // col
  int j = (i < 256) ? i : (i - 256);
  // inv_freq = 10000^(-2j/512); ln(10000) = 9.210340371976184
  double invf = exp(-(double)(2 * j) * (9.210340371976184 / 512.0));
  double a = (double)(T_ - 1 - t) * invf;
  pe[idx] = (i < 256) ? (float)sin(a) : (float)cos(a);
}

// ---------------------------------------------------------------- generic NT GEMM
// C[m,n] = act( sum_k A[m,k] * W[n,k] + bias[n] ), C row-major [M,N].
// AMODE 0: A row-major [M,K].  AMODE 1: A is x[B_,INCH,T_] with m=t*B_+b.
#define BM 128
#define BN 128
#define BK 16
#define LDT 132

template<int AMODE, bool RELU>
__global__ __launch_bounds__(256) void gemm_nt(
    const float* __restrict__ A, const float* __restrict__ W,
    const float* __restrict__ bias, float* __restrict__ C,
    int M, int N, int K)
{
  __shared__ float As[BK][LDT];
  __shared__ float Ws[BK][LDT];
  const int tid = threadIdx.x;
  const int m0 = blockIdx.y * BM;
  const int n0 = blockIdx.x * BN;
  const int row = tid >> 1;          // 0..127
  const int kh  = (tid & 1) * 8;     // 0 or 8
  const int ty  = tid >> 4;          // 0..15
  const int tx  = tid & 15;          // 0..15

  float acc[8][8];
#pragma unroll
  for (int i = 0; i < 8; ++i)
#pragma unroll
    for (int j = 0; j < 8; ++j) acc[i][j] = 0.f;

  for (int kt = 0; kt < K; kt += BK) {
    float a_reg[8], w_reg[8];
    if (AMODE == 0) {
      const float* ap = A + (size_t)(m0 + row) * K + (kt + kh);
      float4 v0 = *(const float4*)ap;
      float4 v1 = *(const float4*)(ap + 4);
      a_reg[0] = v0.x; a_reg[1] = v0.y; a_reg[2] = v0.z; a_reg[3] = v0.w;
      a_reg[4] = v1.x; a_reg[5] = v1.y; a_reg[6] = v1.z; a_reg[7] = v1.w;
    } else {
      int m = m0 + row;
      const float* xp = A + (size_t)(m & 1) * ((size_t)INCH * T_) + (size_t)(kt + kh) * T_ + (m >> 1);
#pragma unroll
      for (int q = 0; q < 8; ++q) a_reg[q] = xp[(size_t)q * T_];
    }
    {
      int nn = n0 + row;
      if (nn < N) {
        const float* wp = W + (size_t)nn * K + (kt + kh);
        float4 v0 = *(const float4*)wp;
        float4 v1 = *(const float4*)(wp + 4);
        w_reg[0] = v0.x; w_reg[1] = v0.y; w_reg[2] = v0.z; w_reg[3] = v0.w;
        w_reg[4] = v1.x; w_reg[5] = v1.y; w_reg[6] = v1.z; w_reg[7] = v1.w;
      } else {
#pragma unroll
        for (int q = 0; q < 8; ++q) w_reg[q] = 0.f;
      }
    }
    __syncthreads();   // previous tile fully consumed
#pragma unroll
    for (int q = 0; q < 8; ++q) { As[kh + q][row] = a_reg[q]; Ws[kh + q][row] = w_reg[q]; }
    __syncthreads();
#pragma unroll
    for (int k = 0; k < BK; ++k) {
      float4 a0 = *(const float4*)&As[k][ty * 4];
      float4 a1 = *(const float4*)&As[k][ty * 4 + 64];
      float4 b0 = *(const float4*)&Ws[k][tx * 4];
      float4 b1 = *(const float4*)&Ws[k][tx * 4 + 64];
      float av[8] = {a0.x, a0.y, a0.z, a0.w, a1.x, a1.y, a1.z, a1.w};
      float bv[8] = {b0.x, b0.y, b0.z, b0.w, b1.x, b1.y, b1.z, b1.w};
#pragma unroll
      for (int i = 0; i < 8; ++i)
#pragma unroll
        for (int j = 0; j < 8; ++j) acc[i][j] += av[i] * bv[j];
    }
  }

#pragma unroll
  for (int ih = 0; ih < 2; ++ih)
#pragma unroll
    for (int i = 0; i < 4; ++i) {
      int m = m0 + ty * 4 + ih * 64 + i;
#pragma unroll
      for (int jh = 0; jh < 2; ++jh) {
        int nn = n0 + tx * 4 + jh * 64;
        if (nn < N) {   // N is a multiple of 64 in all uses
          float b0 = bias ? bias[nn + 0] : 0.f;
          float b1 = bias ? bias[nn + 1] : 0.f;
          float b2 = bias ? bias[nn + 2] : 0.f;
          float b3 = bias ? bias[nn + 3] : 0.f;
          float4 v;
          v.x = acc[ih * 4 + i][jh * 4 + 0] + b0;
          v.y = acc[ih * 4 + i][jh * 4 + 1] + b1;
          v.z = acc[ih * 4 + i][jh * 4 + 2] + b2;
          v.w = acc[ih * 4 + i][jh * 4 + 3] + b3;
          if (RELU) {
            v.x = fmaxf(v.x, 0.f); v.y = fmaxf(v.y, 0.f);
            v.z = fmaxf(v.z, 0.f); v.w = fmaxf(v.w, 0.f);
          }
          *(float4*)&C[(size_t)m * N + nn] = v;
        }
      }
    }
}

// ---------------------------------------------------------------- fused rel-attn
// One block: 32 query rows for one (b,n); flash-style loop over 32-key tiles.
// rel_shift (no mask!) wraps: S[i,j] += Braw[i, j+T-1-i] (j<=i), 0 (j==i+1),
// Braw[i+1, j-i-2] (j>i+1).  With qhat = j+T-1-i we stage Rext[qhat] =
// rk[qhat] (qhat<T), zero-row (qhat==T), rk[qhat-T-1] (qhat>T) and select the
// query row qr[r + (qhat>T)].
#define LDH 68
#define ITILE 32
#define JTILE 32
#define REW 64

__global__ __launch_bounds__(256) void attn_kernel(
    const float* __restrict__ heads, const float* __restrict__ rk,
    const float* __restrict__ rwb, const float* __restrict__ rrb,
    float* __restrict__ avec)
{
  __shared__ float qw[ITILE][LDH];
  __shared__ float qr[ITILE + 1][LDH];
  __shared__ float Ks[JTILE][LDH];
  __shared__ float Vs[JTILE][LDH];
  __shared__ float Re[REW][LDH];
  __shared__ float Ps[ITILE][40];

  const int tid = threadIdx.x;
  const int i0 = blockIdx.x * ITILE;
  const int b  = blockIdx.y & 1;
  const int n  = blockIdx.y >> 1;

  for (int e = tid; e < (ITILE + 1) * 64; e += 256) {
    int rr = e >> 6, d = e & 63;
    int ii = i0 + rr;
    float qv = (ii < T_) ? heads[(size_t)(ii * B_ + b) * 1536 + n * 64 + d] : 0.f;
    qr[rr][d] = qv + rrb[n * 64 + d];
    if (rr < ITILE) qw[rr][d] = qv + rwb[n * 64 + d];
  }

  const int r  = tid >> 3;   // query row within tile (8 threads per row)
  const int jl = tid & 7;
  const int i  = i0 + r;
  const int dh = jl * 8;     // this thread's output-dim slice for PV

  float O[8] = {0, 0, 0, 0, 0, 0, 0, 0};
  float mi = -INFINITY, li = 0.f;

  for (int jt = 0; jt < T_ / JTILE; ++jt) {
    const int j0 = jt * JTILE;
    __syncthreads();  // previous tile's LDS fully consumed (also covers q staging)
    for (int e = tid; e < JTILE * 64; e += 256) {
      int jr = e >> 6, d = e & 63;
      size_t base = (size_t)((j0 + jr) * B_ + b) * 1536 + n * 64 + d;
      Ks[jr][d] = heads[base + 512];
      Vs[jr][d] = heads[base + 1024];
    }
    const int qlo = j0 + (T_ - 1) - (i0 + ITILE - 1);
    for (int e = tid; e < REW * 64; e += 256) {
      int lr = e >> 6, d = e & 63;
      int qh = qlo + lr;
      float v = 0.f;
      if (qh != T_) {
        int p = (qh < T_) ? qh : qh - T_ - 1;
        if (p >= 0 && p < T_) v = rk[(size_t)p * DM + n * 64 + d];
      }
      Re[lr][d] = v;
    }
    __syncthreads();

    float sv[4];
    {
      float ac[4] = {0, 0, 0, 0}, bd[4] = {0, 0, 0, 0};
      const float4* qwp = (const float4*)&qw[r][0];
      const float4* qr0 = (const float4*)&qr[r][0];
      const float4* qr1 = (const float4*)&qr[r + 1][0];
      const float4* kp[4];
      const float4* rp[4];
      int wsel[4];
#pragma unroll
      for (int jj = 0; jj < 4; ++jj) {
        int jloc = jl + 8 * jj;
        int qh = (j0 + jloc) + (T_ - 1) - i;
        kp[jj] = (const float4*)&Ks[jloc][0];
        rp[jj] = (const float4*)&Re[qh - qlo][0];
        wsel[jj] = (qh > T_) ? 1 : 0;
      }
#pragma unroll
      for (int d4 = 0; d4 < 16; ++d4) {
        float4 aw = qwp[d4];
        float4 a0 = qr0[d4];
        float4 a1 = qr1[d4];
#pragma unroll
        for (int jj = 0; jj < 4; ++jj) {
          float4 kk = kp[jj][d4];
          ac[jj] += aw.x * kk.x + aw.y * kk.y + aw.z * kk.z + aw.w * kk.w;
          float4 rv = rp[jj][d4];
          float qx = wsel[jj] ? a1.x : a0.x;
          float qy = wsel[jj] ? a1.y : a0.y;
          float qz = wsel[jj] ? a1.z : a0.z;
          float qq = wsel[jj] ? a1.w : a0.w;
          bd[jj] += qx * rv.x + qy * rv.y + qz * rv.z + qq * rv.w;
        }
      }
#pragma unroll
      for (int jj = 0; jj < 4; ++jj) sv[jj] = (ac[jj] + bd[jj]) * 0.125f;
    }

    // online softmax over this row (8 sibling lanes, same wave)
    float lm = fmaxf(fmaxf(sv[0], sv[1]), fmaxf(sv[2], sv[3]));
#pragma unroll
    for (int o = 1; o < 8; o <<= 1) lm = fmaxf(lm, __shfl_xor(lm, o));
    float mnew = fmaxf(mi, lm);
    float alpha = __expf(mi - mnew);   // first iter: exp(-inf)=0
    float ls = 0.f;
#pragma unroll
    for (int jj = 0; jj < 4; ++jj) {
      float p = __expf(sv[jj] - mnew);
      Ps[r][jl + 8 * jj] = p;
      ls += p;
    }
#pragma unroll
    for (int o = 1; o < 8; o <<= 1) ls += __shfl_xor(ls, o);
    li = li * alpha + ls;
    mi = mnew;
    __syncthreads();

#pragma unroll
    for (int dd = 0; dd < 8; ++dd) O[dd] *= alpha;
    for (int j = 0; j < JTILE; ++j) {
      float p = Ps[r][j];
      const float4* vp = (const float4*)&Vs[j][dh];
      float4 v0 = vp[0], v1 = vp[1];
      O[0] += p * v0.x; O[1] += p * v0.y; O[2] += p * v0.z; O[3] += p * v0.w;
      O[4] += p * v1.x; O[5] += p * v1.y; O[6] += p * v1.z; O[7] += p * v1.w;
    }
  }

  float inv = 1.f / li;
  float* op = &avec[(size_t)(i * B_ + b) * DM + n * 64 + dh];
  float4 o0 = { O[0] * inv, O[1] * inv, O[2] * inv, O[3] * inv };
  float4 o1 = { O[4] * inv, O[5] * inv, O[6] * inv, O[7] * inv };
  *(float4*)op = o0;
  *(float4*)(op + 4) = o1;
}

// ---------------------------------------------------------------- LN(residual)
// h[m,:] = LN(h[m,:] + delta[m,:]) * s + b     (in-place on h)
__global__ __launch_bounds__(256) void ln_res_kernel(
    float* __restrict__ h, const float* __restrict__ delta,
    const float* __restrict__ s, const float* __restrict__ bb)
{
  const int m = blockIdx.x;
  const int tid = threadIdx.x;
  float* hp = h + (size_t)m * DM;
  const float* dp = delta + (size_t)m * DM;
  float x0 = hp[tid] + dp[tid];
  float x1 = hp[tid + 256] + dp[tid + 256];
  float sum = x0 + x1, sq = x0 * x0 + x1 * x1;
#pragma unroll
  for (int o = 32; o > 0; o >>= 1) { sum += __shfl_down(sum, o); sq += __shfl_down(sq, o); }
  __shared__ float part[8];
  int wv = tid >> 6;
  if ((tid & 63) == 0) { part[wv * 2] = sum; part[wv * 2 + 1] = sq; }
  __syncthreads();
  float ts = part[0] + part[2] + part[4] + part[6];
  float tq = part[1] + part[3] + part[5] + part[7];
  float mu = ts * (1.f / DM);
  float var = tq * (1.f / DM) - mu * mu;
  float rs = rsqrtf(var + 1e-5f);
  hp[tid]       = (x0 - mu) * rs * s[tid]       + bb[tid];
  hp[tid + 256] = (x1 - mu) * rs * s[tid + 256] + bb[tid + 256];
}

// ---------------------------------------------------------------- classifier reorder
__global__ __launch_bounds__(256) void reorder_kernel(const float* __restrict__ ct,
                                                      float* __restrict__ out) {
  int idx = blockIdx.x * 256 + threadIdx.x;
  if (idx >= B_ * NCLS * T_) return;
  int t  = idx & (T_ - 1);
  int nc = (idx >> 11) & 63;
  int bb = idx >> 17;
  out[idx] = ct[(size_t)(t * B_ + bb) * NCLS + nc];
}

// ---------------------------------------------------------------- launch
extern "C" void kernel_launch(void* const* d_in, const int* in_sizes, int n_in,
                              void* d_out, int out_size, void* d_ws, size_t ws_size,
                              hipStream_t stream)
{
  const float* x     = (const float*)d_in[0];
  const float* emb_w = (const float*)d_in[1];
  const float* emb_b = (const float*)d_in[2];
  const float* rwb   = (const float*)d_in[3];
  const float* rrb   = (const float*)d_in[4];
  const float* qkv_w = (const float*)d_in[5];
  const float* qkv_b = (const float*)d_in[6];
  const float* rproj = (const float*)d_in[7];
  const float* o_w   = (const float*)d_in[8];
  const float* ln1s  = (const float*)d_in[9];
  const float* ln1b  = (const float*)d_in[10];
  const float* ff1w  = (const float*)d_in[11];
  const float* ff1b  = (const float*)d_in[12];
  const float* ff2w  = (const float*)d_in[13];
  const float* ff2b  = (const float*)d_in[14];
  const float* ln2s  = (const float*)d_in[15];
  const float* ln2b  = (const float*)d_in[16];
  const float* clsw  = (const float*)d_in[17];
  const float* clsb  = (const float*)d_in[18];
  float* out = (float*)d_out;

  float* ws    = (float*)d_ws;
  float* h     = ws;                              // MT*DM
  float* heads = h + (size_t)MT * DM;             // MT*3*DM
  float* pe    = heads + (size_t)MT * 3 * DM;     // T_*DM
  float* rk    = pe + (size_t)T_ * DM;            // T_*DM
  float* avec  = rk + (size_t)T_ * DM;            // MT*DM
  float* tmp   = avec + (size_t)MT * DM;          // MT*DI (32MB), shared temp

  pos_kernel<<<(T_ * DM) / 256, 256, 0, stream>>>(pe);
  gemm_nt<1, false><<<dim3(DM / BN, MT / BM), 256, 0, stream>>>(x, emb_w, emb_b, h, MT, DM, INCH);

  for (int l = 0; l < 4; ++l) {
    gemm_nt<0, false><<<dim3(1536 / BN, MT / BM), 256, 0, stream>>>(
        h, qkv_w + (size_t)l * 1536 * DM, qkv_b + l * 1536, heads, MT, 1536, DM);
    gemm_nt<0, false><<<dim3(DM / BN, T_ / BM), 256, 0, stream>>>(
        pe, rproj + (size_t)l * DM * DM, nullptr, rk, T_, DM, DM);
    attn_kernel<<<dim3(T_ / ITILE, B_ * NH), 256, 0, stream>>>(heads, rk, rwb, rrb, avec);
    gemm_nt<0, false><<<dim3(DM / BN, MT / BM), 256, 0, stream>>>(
        avec, o_w + (size_t)l * DM * DM, nullptr, tmp, MT, DM, DM);
    ln_res_kernel<<<MT, 256, 0, stream>>>(h, tmp, ln1s + l * DM, ln1b + l * DM);
    gemm_nt<0, true><<<dim3(DI / BN, MT / BM), 256, 0, stream>>>(
        h, ff1w + (size_t)l * DI * DM, ff1b + l * DI, tmp, MT, DI, DM);
    gemm_nt<0, false><<<dim3(DM / BN, MT / BM), 256, 0, stream>>>(
        tmp, ff2w + (size_t)l * DM * DI, ff2b + l * DM, avec, MT, DM, DI);
    ln_res_kernel<<<MT, 256, 0, stream>>>(h, avec, ln2s + l * DM, ln2b + l * DM);
  }

  gemm_nt<0, false><<<dim3(1, MT / BM), 256, 0, stream>>>(h, clsw, clsb, tmp, MT, NCLS, DM);
  reorder_kernel<<<(B_ * NCLS * T_) / 256, 256, 0, stream>>>(tmp, out);
}

// Round 2
// 5038.826 us; speedup vs baseline: 2.3112x; 2.3112x over previous
//
#include <hip/hip_runtime.h>
#include <math.h>

// TransformerXL forward. fp32 GEMMs + bf16-MFMA flash attention.
// Layout: all [t,b,*] tensors flattened with m = t*B_ + b.

#define T_   2048
#define B_   2
#define DM   512
#define NH   8
#define DH   64
#define DI   2048
#define INCH 2048
#define NCLS 64
#define MT   4096   // T_*B_

typedef __attribute__((ext_vector_type(8))) short short8;
typedef __attribute__((ext_vector_type(4))) float float4v;

__device__ inline ushort f2bf(float f) {
  uint u = __float_as_uint(f);
  return (ushort)((u + 0x7FFFu + ((u >> 16) & 1u)) >> 16);   // RNE
}
__device__ inline float bf2f(ushort h) { return __uint_as_float(((uint)h) << 16); }

// ---------------------------------------------------------------- pos emb
__global__ __launch_bounds__(256) void pos_kernel(float* __restrict__ pe) {
  int idx = blockIdx.x * 256 + threadIdx.x;
  if (idx >= T_ * DM) return;
  int t = idx >> 9;
  int i = idx & 511;
  int j = (i < 256) ? i : (i - 256);
  double invf = exp(-(double)(2 * j) * (9.210340371976184 / 512.0));
  double a = (double)(T_ - 1 - t) * invf;
  pe[idx] = (i < 256) ? (float)sin(a) : (float)cos(a);
}

// ---------------------------------------------------------------- generic NT GEMM (fp32)
#define BM 128
#define BN 128
#define BK 16
#define LDT 132

template<int AMODE, bool RELU>
__global__ __launch_bounds__(256) void gemm_nt(
    const float* __restrict__ A, const float* __restrict__ W,
    const float* __restrict__ bias, float* __restrict__ C,
    int M, int N, int K)
{
  __shared__ float As[BK][LDT];
  __shared__ float Ws[BK][LDT];
  const int tid = threadIdx.x;
  const int m0 = blockIdx.y * BM;
  const int n0 = blockIdx.x * BN;
  const int row = tid >> 1;
  const int kh  = (tid & 1) * 8;
  const int ty  = tid >> 4;
  const int tx  = tid & 15;

  float acc[8][8];
#pragma unroll
  for (int i = 0; i < 8; ++i)
#pragma unroll
    for (int j = 0; j < 8; ++j) acc[i][j] = 0.f;

  for (int kt = 0; kt < K; kt += BK) {
    float a_reg[8], w_reg[8];
    if (AMODE == 0) {
      const float* ap = A + (size_t)(m0 + row) * K + (kt + kh);
      float4 v0 = *(const float4*)ap;
      float4 v1 = *(const float4*)(ap + 4);
      a_reg[0] = v0.x; a_reg[1] = v0.y; a_reg[2] = v0.z; a_reg[3] = v0.w;
      a_reg[4] = v1.x; a_reg[5] = v1.y; a_reg[6] = v1.z; a_reg[7] = v1.w;
    } else {
      int m = m0 + row;
      const float* xp = A + (size_t)(m & 1) * ((size_t)INCH * T_) + (size_t)(kt + kh) * T_ + (m >> 1);
#pragma unroll
      for (int q = 0; q < 8; ++q) a_reg[q] = xp[(size_t)q * T_];
    }
    {
      int nn = n0 + row;
      if (nn < N) {
        const float* wp = W + (size_t)nn * K + (kt + kh);
        float4 v0 = *(const float4*)wp;
        float4 v1 = *(const float4*)(wp + 4);
        w_reg[0] = v0.x; w_reg[1] = v0.y; w_reg[2] = v0.z; w_reg[3] = v0.w;
        w_reg[4] = v1.x; w_reg[5] = v1.y; w_reg[6] = v1.z; w_reg[7] = v1.w;
      } else {
#pragma unroll
        for (int q = 0; q < 8; ++q) w_reg[q] = 0.f;
      }
    }
    __syncthreads();
#pragma unroll
    for (int q = 0; q < 8; ++q) { As[kh + q][row] = a_reg[q]; Ws[kh + q][row] = w_reg[q]; }
    __syncthreads();
#pragma unroll
    for (int k = 0; k < BK; ++k) {
      float4 a0 = *(const float4*)&As[k][ty * 4];
      float4 a1 = *(const float4*)&As[k][ty * 4 + 64];
      float4 b0 = *(const float4*)&Ws[k][tx * 4];
      float4 b1 = *(const float4*)&Ws[k][tx * 4 + 64];
      float av[8] = {a0.x, a0.y, a0.z, a0.w, a1.x, a1.y, a1.z, a1.w};
      float bv[8] = {b0.x, b0.y, b0.z, b0.w, b1.x, b1.y, b1.z, b1.w};
#pragma unroll
      for (int i = 0; i < 8; ++i)
#pragma unroll
        for (int j = 0; j < 8; ++j) acc[i][j] += av[i] * bv[j];
    }
  }

#pragma unroll
  for (int ih = 0; ih < 2; ++ih)
#pragma unroll
    for (int i = 0; i < 4; ++i) {
      int m = m0 + ty * 4 + ih * 64 + i;
#pragma unroll
      for (int jh = 0; jh < 2; ++jh) {
        int nn = n0 + tx * 4 + jh * 64;
        if (nn < N) {
          float b0 = bias ? bias[nn + 0] : 0.f;
          float b1 = bias ? bias[nn + 1] : 0.f;
          float b2 = bias ? bias[nn + 2] : 0.f;
          float b3 = bias ? bias[nn + 3] : 0.f;
          float4 v;
          v.x = acc[ih * 4 + i][jh * 4 + 0] + b0;
          v.y = acc[ih * 4 + i][jh * 4 + 1] + b1;
          v.z = acc[ih * 4 + i][jh * 4 + 2] + b2;
          v.w = acc[ih * 4 + i][jh * 4 + 3] + b3;
          if (RELU) {
            v.x = fmaxf(v.x, 0.f); v.y = fmaxf(v.y, 0.f);
            v.z = fmaxf(v.z, 0.f); v.w = fmaxf(v.w, 0.f);
          }
          *(float4*)&C[(size_t)m * N + nn] = v;
        }
      }
    }
}

// ---------------------------------------------------------------- MFMA flash rel-attn
// Block: 32 query rows of one (b,n). Key tiles of 64. 4 waves.
// rel_shift (no mask) wraps: BD[i,j] = Qr[i+sel] . Rext[qh], qh = j+T-1-i,
// sel = (qh > T); Rext[qh<T]=rk[qh], Rext[T]=0, Rext[qh>T]=rk[qh-T-1].
// G[rr][w] = Qr[i0+rr] . Rext[qmin+w]  (qmin = j0 + 2016 - i0, w = c+31-r).
#define AST 72    // ushort stride, 144 B rows (16B-aligned for b128 frags)
#define VST 74    // Vt stride: 148 B rows (dword-aligned; conflict-free transpose writes)
#define GST 100   // Gb stride (ushort)

__global__ __launch_bounds__(256) void attn_mfma_kernel(
    const float* __restrict__ heads, const float* __restrict__ rk,
    const float* __restrict__ rwb, const float* __restrict__ rrb,
    float* __restrict__ avec)
{
  __shared__ __attribute__((aligned(16))) ushort Qw[32 * AST];
  __shared__ __attribute__((aligned(16))) ushort Qr[48 * AST];
  __shared__ __attribute__((aligned(16))) ushort Ks[64 * AST];
  __shared__ __attribute__((aligned(16))) ushort Vt[64 * VST];
  __shared__ __attribute__((aligned(16))) ushort Re[96 * AST];
  __shared__ __attribute__((aligned(16))) ushort Sb[32 * AST];
  __shared__ __attribute__((aligned(16))) ushort Gb[48 * GST];
  __shared__ __attribute__((aligned(16))) ushort Pb[32 * AST];
  __shared__ float alphaB[32];
  __shared__ float liB[32];

  const int tid  = threadIdx.x;
  const int i0   = blockIdx.x * 32;
  const int b    = blockIdx.y & 1;
  const int n    = blockIdx.y >> 1;
  const int wave = tid >> 6;
  const int lane = tid & 63;
  const int quad = lane >> 4;
  const int lidx = lane & 15;

  // ---- stage Q tiles once (Qr needs rows i0..i0+47; zero past T)
  for (int e = tid; e < 48 * 64; e += 256) {
    int rr = e >> 6, d = e & 63;
    int ii = i0 + rr;
    float qv = (ii < T_) ? heads[(size_t)(ii * B_ + b) * 1536 + n * 64 + d] : 0.f;
    Qr[rr * AST + d] = f2bf(qv + rrb[n * 64 + d]);
    if (rr < 32) Qw[rr * AST + d] = f2bf(qv + rwb[n * 64 + d]);
  }

  float acc[2][4] = {{0.f, 0.f, 0.f, 0.f}, {0.f, 0.f, 0.f, 0.f}};
  float mi = -INFINITY, li = 0.f;
  const int r  = tid >> 3;          // softmax row (0..31)
  const int c0 = (tid & 7) * 8;     // softmax col base

  for (int jt = 0; jt < 32; ++jt) {
    const int j0 = jt * 64;
    const int qmin = j0 + 2016 - i0;
    __syncthreads();   // prev iter's PV done; LDS free

    // stage K [key][dim] bf16 (coalesced float4)
    for (int e4 = tid; e4 < 1024; e4 += 256) {
      int key = e4 >> 4, d4 = (e4 & 15) * 4;
      float4 v = *(const float4*)&heads[(size_t)((j0 + key) * B_ + b) * 1536 + 512 + n * 64 + d4];
      ushort4 w4 = { f2bf(v.x), f2bf(v.y), f2bf(v.z), f2bf(v.w) };
      *(ushort4*)&Ks[key * AST + d4] = w4;
    }
    // stage V transposed [dim][key], packed key-pairs (dword writes, ~2-way)
    for (int e = tid; e < 2048; e += 256) {
      int d = e & 63, kp = e >> 6;
      size_t base = (size_t)((j0 + 2 * kp) * B_ + b) * 1536 + 1024 + n * 64 + d;
      float v0 = heads[base];
      float v1 = heads[base + 2 * 1536];
      uint pk = (uint)f2bf(v0) | ((uint)f2bf(v1) << 16);
      *(uint*)&Vt[d * VST + 2 * kp] = pk;
    }
    // stage Rext window rows qmin..qmin+95
    for (int e4 = tid; e4 < 96 * 16; e4 += 256) {
      int rr = e4 >> 4, d4 = (e4 & 15) * 4;
      int qh = qmin + rr;
      float4 v = {0.f, 0.f, 0.f, 0.f};
      if (qh != T_) {
        int p = (qh < T_) ? qh : qh - T_ - 1;
        v = *(const float4*)&rk[(size_t)p * DM + n * 64 + d4];
      }
      ushort4 w4 = { f2bf(v.x), f2bf(v.y), f2bf(v.z), f2bf(v.w) };
      *(ushort4*)&Re[rr * AST + d4] = w4;
    }
    __syncthreads();

    // AC tiles: S[32][64] = Qw . K^T   (2 tiles per wave)
#pragma unroll
    for (int q = 0; q < 2; ++q) {
      int t2 = wave * 2 + q, s = t2 >> 2, ct = t2 & 3;
      float4v c = {0.f, 0.f, 0.f, 0.f};
#pragma unroll
      for (int kb = 0; kb < 2; ++kb) {
        short8 a  = *(const short8*)&Qw[(s * 16 + lidx) * AST + kb * 32 + quad * 8];
        short8 bk = *(const short8*)&Ks[(ct * 16 + lidx) * AST + kb * 32 + quad * 8];
        c = __builtin_amdgcn_mfma_f32_16x16x32_bf16(a, bk, c, 0, 0, 0);
      }
#pragma unroll
      for (int reg = 0; reg < 4; ++reg)
        Sb[(s * 16 + quad * 4 + reg) * AST + ct * 16 + lidx] = f2bf(c[reg]);
    }
    // G tiles: rows 0..47 (strip2 only cols<64 needed) -> 16 tiles, 4/wave
    for (int g = wave; g < 16; g += 4) {
      int sg = (g < 12) ? (g / 6) : 2;
      int ct = (g < 12) ? (g % 6) : (g - 12);
      float4v c = {0.f, 0.f, 0.f, 0.f};
#pragma unroll
      for (int kb = 0; kb < 2; ++kb) {
        short8 a  = *(const short8*)&Qr[(sg * 16 + lidx) * AST + kb * 32 + quad * 8];
        short8 br = *(const short8*)&Re[(ct * 16 + lidx) * AST + kb * 32 + quad * 8];
        c = __builtin_amdgcn_mfma_f32_16x16x32_bf16(a, br, c, 0, 0, 0);
      }
#pragma unroll
      for (int reg = 0; reg < 4; ++reg)
        Gb[(sg * 16 + quad * 4 + reg) * GST + ct * 16 + lidx] = f2bf(c[reg]);
    }
    __syncthreads();

    // online softmax: thread owns row r, cols c0..c0+7
    {
      short8 sv = *(const short8*)&Sb[r * AST + c0];
      float x[8];
#pragma unroll
      for (int k = 0; k < 8; ++k) {
        int w  = c0 + k + 31 - r;
        int qh = qmin + w;
        int sel = (qh > T_) ? 1 : 0;
        float bd = bf2f(Gb[(r + sel) * GST + w]);
        x[k] = (bf2f((ushort)sv[k]) + bd) * 0.125f;
      }
      float lm = x[0];
#pragma unroll
      for (int k = 1; k < 8; ++k) lm = fmaxf(lm, x[k]);
      lm = fmaxf(lm, __shfl_xor(lm, 1));
      lm = fmaxf(lm, __shfl_xor(lm, 2));
      lm = fmaxf(lm, __shfl_xor(lm, 4));
      float mnew = fmaxf(mi, lm);
      float al = __expf(mi - mnew);
      float ls = 0.f;
      short8 pv8;
#pragma unroll
      for (int k = 0; k < 8; ++k) {
        float p = __expf(x[k] - mnew);
        ls += p;
        ((ushort*)&pv8)[k] = f2bf(p);
      }
      ls += __shfl_xor(ls, 1);
      ls += __shfl_xor(ls, 2);
      ls += __shfl_xor(ls, 4);
      li = li * al + ls;
      mi = mnew;
      *(short8*)&Pb[r * AST + c0] = pv8;
      if ((tid & 7) == 0) alphaB[r] = al;
    }
    __syncthreads();

    // PV: D += P . V  (2 accum tiles per wave, persistent)
#pragma unroll
    for (int q = 0; q < 2; ++q) {
      int t2 = wave * 2 + q, s = t2 >> 2, dt = t2 & 3;
      float4v c;
#pragma unroll
      for (int reg = 0; reg < 4; ++reg)
        c[reg] = acc[q][reg] * alphaB[s * 16 + quad * 4 + reg];
#pragma unroll
      for (int kb = 0; kb < 2; ++kb) {
        short8 a = *(const short8*)&Pb[(s * 16 + lidx) * AST + kb * 32 + quad * 8];
        union { short8 v; uint u[4]; } bv;
        const uint* vp = (const uint*)&Vt[(dt * 16 + lidx) * VST + kb * 32 + quad * 8];
        bv.u[0] = vp[0]; bv.u[1] = vp[1]; bv.u[2] = vp[2]; bv.u[3] = vp[3];
        c = __builtin_amdgcn_mfma_f32_16x16x32_bf16(a, bv.v, c, 0, 0, 0);
      }
#pragma unroll
      for (int reg = 0; reg < 4; ++reg) acc[q][reg] = c[reg];
    }
  }

  if ((tid & 7) == 0) liB[r] = li;
  __syncthreads();
#pragma unroll
  for (int q = 0; q < 2; ++q) {
    int t2 = wave * 2 + q, s = t2 >> 2, dt = t2 & 3;
#pragma unroll
    for (int reg = 0; reg < 4; ++reg) {
      int row = s * 16 + quad * 4 + reg;
      float val = acc[q][reg] / liB[row];
      int i = i0 + row;
      avec[(size_t)(i * B_ + b) * DM + n * 64 + dt * 16 + lidx] = val;
    }
  }
}

// ---------------------------------------------------------------- LN(residual)
__global__ __launch_bounds__(256) void ln_res_kernel(
    float* __restrict__ h, const float* __restrict__ delta,
    const float* __restrict__ s, const float* __restrict__ bb)
{
  const int m = blockIdx.x;
  const int tid = threadIdx.x;
  float* hp = h + (size_t)m * DM;
  const float* dp = delta + (size_t)m * DM;
  float x0 = hp[tid] + dp[tid];
  float x1 = hp[tid + 256] + dp[tid + 256];
  float sum = x0 + x1, sq = x0 * x0 + x1 * x1;
#pragma unroll
  for (int o = 32; o > 0; o >>= 1) { sum += __shfl_down(sum, o); sq += __shfl_down(sq, o); }
  __shared__ float part[8];
  int wv = tid >> 6;
  if ((tid & 63) == 0) { part[wv * 2] = sum; part[wv * 2 + 1] = sq; }
  __syncthreads();
  float ts = part[0] + part[2] + part[4] + part[6];
  float tq = part[1] + part[3] + part[5] + part[7];
  float mu = ts * (1.f / DM);
  float var = tq * (1.f / DM) - mu * mu;
  float rs = rsqrtf(var + 1e-5f);
  hp[tid]       = (x0 - mu) * rs * s[tid]       + bb[tid];
  hp[tid + 256] = (x1 - mu) * rs * s[tid + 256] + bb[tid + 256];
}

// ---------------------------------------------------------------- classifier reorder
__global__ __launch_bounds__(256) void reorder_kernel(const float* __restrict__ ct,
                                                      float* __restrict__ out) {
  int idx = blockIdx.x * 256 + threadIdx.x;
  if (idx >= B_ * NCLS * T_) return;
  int t  = idx & (T_ - 1);
  int nc = (idx >> 11) & 63;
  int bb = idx >> 17;
  out[idx] = ct[(size_t)(t * B_ + bb) * NCLS + nc];
}

// ---------------------------------------------------------------- launch
extern "C" void kernel_launch(void* const* d_in, const int* in_sizes, int n_in,
                              void* d_out, int out_size, void* d_ws, size_t ws_size,
                              hipStream_t stream)
{
  const float* x     = (const float*)d_in[0];
  const float* emb_w = (const float*)d_in[1];
  const float* emb_b = (const float*)d_in[2];
  const float* rwb   = (const float*)d_in[3];
  const float* rrb   = (const float*)d_in[4];
  const float* qkv_w = (const float*)d_in[5];
  const float* qkv_b = (const float*)d_in[6];
  const float* rproj = (const float*)d_in[7];
  const float* o_w   = (const float*)d_in[8];
  const float* ln1s  = (const float*)d_in[9];
  const float* ln1b  = (const float*)d_in[10];
  const float* ff1w  = (const float*)d_in[11];
  const float* ff1b  = (const float*)d_in[12];
  const float* ff2w  = (const float*)d_in[13];
  const float* ff2b  = (const float*)d_in[14];
  const float* ln2s  = (const float*)d_in[15];
  const float* ln2b  = (const float*)d_in[16];
  const float* clsw  = (const float*)d_in[17];
  const float* clsb  = (const float*)d_in[18];
  float* out = (float*)d_out;

  float* ws    = (float*)d_ws;
  float* h     = ws;                              // MT*DM
  float* heads = h + (size_t)MT * DM;             // MT*3*DM
  float* pe    = heads + (size_t)MT * 3 * DM;     // T_*DM
  float* rk    = pe + (size_t)T_ * DM;            // T_*DM
  float* avec  = rk + (size_t)T_ * DM;            // MT*DM
  float* tmp   = avec + (size_t)MT * DM;          // MT*DI

  pos_kernel<<<(T_ * DM) / 256, 256, 0, stream>>>(pe);
  gemm_nt<1, false><<<dim3(DM / BN, MT / BM), 256, 0, stream>>>(x, emb_w, emb_b, h, MT, DM, INCH);

  for (int l = 0; l < 4; ++l) {
    gemm_nt<0, false><<<dim3(1536 / BN, MT / BM), 256, 0, stream>>>(
        h, qkv_w + (size_t)l * 1536 * DM, qkv_b + l * 1536, heads, MT, 1536, DM);
    gemm_nt<0, false><<<dim3(DM / BN, T_ / BM), 256, 0, stream>>>(
        pe, rproj + (size_t)l * DM * DM, nullptr, rk, T_, DM, DM);
    attn_mfma_kernel<<<dim3(T_ / 32, B_ * NH), 256, 0, stream>>>(heads, rk, rwb, rrb, avec);
    gemm_nt<0, false><<<dim3(DM / BN, MT / BM), 256, 0, stream>>>(
        avec, o_w + (size_t)l * DM * DM, nullptr, tmp, MT, DM, DM);
    ln_res_kernel<<<MT, 256, 0, stream>>>(h, tmp, ln1s + l * DM, ln1b + l * DM);
    gemm_nt<0, true><<<dim3(DI / BN, MT / BM), 256, 0, stream>>>(
        h, ff1w + (size_t)l * DI * DM, ff1b + l * DI, tmp, MT, DI, DM);
    gemm_nt<0, false><<<dim3(DM / BN, MT / BM), 256, 0, stream>>>(
        tmp, ff2w + (size_t)l * DM * DI, ff2b + l * DM, avec, MT, DM, DI);
    ln_res_kernel<<<MT, 256, 0, stream>>>(h, avec, ln2s + l * DM, ln2b + l * DM);
  }

  gemm_nt<0, false><<<dim3(1, MT / BM), 256, 0, stream>>>(h, clsw, clsb, tmp, MT, NCLS, DM);
  reorder_kernel<<<(B_ * NCLS * T_) / 256, 256, 0, stream>>>(tmp, out);
}

// Round 3
// 2119.674 us; speedup vs baseline: 5.4941x; 2.3772x over previous
//
#include <hip/hip_runtime.h>
#include <math.h>

// TransformerXL forward. bf16-MFMA GEMMs (m97-style global_load_lds staging)
// + bf16-MFMA flash attention. Layout: [t,b,*] flattened, m = t*B_ + b.

#define T_   2048
#define B_   2
#define DM   512
#define NH   8
#define DH   64
#define DI   2048
#define INCH 2048
#define NCLS 64
#define MT   4096   // T_*B_

typedef __attribute__((ext_vector_type(8))) short short8;
typedef __attribute__((ext_vector_type(4))) float float4v;

__device__ inline ushort f2bf(float f) {
  uint u = __float_as_uint(f);
  return (ushort)((u + 0x7FFFu + ((u >> 16) & 1u)) >> 16);   // RNE
}
__device__ inline float bf2f(ushort h) { return __uint_as_float(((uint)h) << 16); }

__device__ inline void gload16(const void* g, void* lds) {
  __builtin_amdgcn_global_load_lds(
      (const __attribute__((address_space(1))) void*)g,
      (__attribute__((address_space(3))) void*)lds, 16, 0, 0);
}

// ---------------------------------------------------------------- pos emb (bf16 out)
__global__ __launch_bounds__(256) void pos_kernel(ushort* __restrict__ pe) {
  int idx = blockIdx.x * 256 + threadIdx.x;
  if (idx >= T_ * DM) return;
  int t = idx >> 9;
  int i = idx & 511;
  int j = (i < 256) ? i : (i - 256);
  double invf = exp(-(double)(2 * j) * (9.210340371976184 / 512.0));
  double a = (double)(T_ - 1 - t) * invf;
  pe[idx] = f2bf((i < 256) ? (float)sin(a) : (float)cos(a));
}

// ---------------------------------------------------------------- fp32 -> bf16 convert
__global__ __launch_bounds__(256) void cvt_kernel(const float* __restrict__ src,
                                                  ushort* __restrict__ dst, int n4) {
  int i = blockIdx.x * 256 + threadIdx.x;
  if (i >= n4) return;
  float4 v = ((const float4*)src)[i];
  ushort4 w = { f2bf(v.x), f2bf(v.y), f2bf(v.z), f2bf(v.w) };
  ((ushort4*)dst)[i] = w;
}

// ---------------------------------------------------------------- x[B,C,T] -> xb[(t*2+b), C] bf16
__global__ __launch_bounds__(256) void xpose_kernel(const float* __restrict__ x,
                                                    ushort* __restrict__ xb) {
  __shared__ float s[32][33];
  int t0 = blockIdx.x * 32, k0 = blockIdx.y * 32, b = blockIdx.z;
  int tx = threadIdx.x & 31, ty = threadIdx.x >> 5;   // ty 0..7
#pragma unroll
  for (int l = 0; l < 4; ++l) {
    int k = k0 + ty + l * 8;
    s[ty + l * 8][tx] = x[((size_t)b * INCH + k) * T_ + t0 + tx];
  }
  __syncthreads();
#pragma unroll
  for (int l = 0; l < 4; ++l) {
    int t = t0 + ty + l * 8;
    xb[((size_t)(t * 2 + b)) * INCH + k0 + tx] = f2bf(s[tx][ty + l * 8]);
  }
}

// ---------------------------------------------------------------- bf16 MFMA GEMM
// C[m,n] = act( sum_k A[m,k]*W[n,k] + bias[n] ).  A[M,K], W[N,K] bf16 row-major.
// OUTMODE: 0 fp32 only, 1 bf16 only, 2 both. M,N multiples of 128; K of 32.
template<int OUTMODE, bool RELU>
__global__ __launch_bounds__(256) void gemm_bf16(
    const ushort* __restrict__ A, const ushort* __restrict__ W,
    const float* __restrict__ bias, float* __restrict__ Cf, ushort* __restrict__ Cb,
    int M, int N, int K)
{
  __shared__ __attribute__((aligned(16))) ushort As[128 * 32];
  __shared__ __attribute__((aligned(16))) ushort Bs[128 * 32];
  const int tid  = threadIdx.x;
  const int wave = tid >> 6, lane = tid & 63;
  const int quad = lane >> 4, lidx = lane & 15;
  const int m0 = blockIdx.y * 128, n0 = blockIdx.x * 128;
  const int srow  = lane >> 2;        // row within 16-row chunk
  const int selem = (lane & 3) * 8;   // ushort offset within 64-B row

  float4v acc[16];
#pragma unroll
  for (int i = 0; i < 16; ++i) acc[i] = (float4v){0.f, 0.f, 0.f, 0.f};

  const int wm = (wave >> 1) * 64, wn = (wave & 1) * 64;

  for (int k0 = 0; k0 < K; k0 += 32) {
    __syncthreads();   // prev iter's fragment reads done
    const ushort* ga0 = A + (size_t)(m0 + wave * 16 + srow) * K + k0 + selem;
    const ushort* gb0 = W + (size_t)(n0 + wave * 16 + srow) * K + k0 + selem;
    gload16(ga0,                 &As[wave * 512]);
    gload16(ga0 + (size_t)64 * K, &As[2048 + wave * 512]);
    gload16(gb0,                 &Bs[wave * 512]);
    gload16(gb0 + (size_t)64 * K, &Bs[2048 + wave * 512]);
    __syncthreads();   // drains vmcnt (global_load_lds) before use

    short8 af[4], bf[4];
#pragma unroll
    for (int i = 0; i < 4; ++i) af[i] = *(const short8*)&As[(wm + i * 16 + lidx) * 32 + quad * 8];
#pragma unroll
    for (int j = 0; j < 4; ++j) bf[j] = *(const short8*)&Bs[(wn + j * 16 + lidx) * 32 + quad * 8];
#pragma unroll
    for (int i = 0; i < 4; ++i)
#pragma unroll
      for (int j = 0; j < 4; ++j)
        acc[i * 4 + j] = __builtin_amdgcn_mfma_f32_16x16x32_bf16(af[i], bf[j], acc[i * 4 + j], 0, 0, 0);
  }

  float bj[4];
#pragma unroll
  for (int j = 0; j < 4; ++j) bj[j] = bias ? bias[n0 + wn + j * 16 + lidx] : 0.f;
#pragma unroll
  for (int i = 0; i < 4; ++i) {
    int rbase = m0 + wm + i * 16 + quad * 4;
#pragma unroll
    for (int j = 0; j < 4; ++j) {
      int col = n0 + wn + j * 16 + lidx;
#pragma unroll
      for (int reg = 0; reg < 4; ++reg) {
        float v = acc[i * 4 + j][reg] + bj[j];
        if (RELU) v = fmaxf(v, 0.f);
        size_t off = (size_t)(rbase + reg) * N + col;
        if (OUTMODE != 1) Cf[off] = v;
        if (OUTMODE != 0) Cb[off] = f2bf(v);
      }
    }
  }
}

// ---------------------------------------------------------------- fp32 GEMM (cls only)
#define BM 128
#define BN 128
#define BK 16
#define LDT 132

__global__ __launch_bounds__(256) void gemm_f32(
    const float* __restrict__ A, const float* __restrict__ W,
    const float* __restrict__ bias, float* __restrict__ C,
    int M, int N, int K)
{
  __shared__ float Asm[BK][LDT];
  __shared__ float Wsm[BK][LDT];
  const int tid = threadIdx.x;
  const int m0 = blockIdx.y * BM;
  const int n0 = blockIdx.x * BN;
  const int row = tid >> 1;
  const int kh  = (tid & 1) * 8;
  const int ty  = tid >> 4;
  const int tx  = tid & 15;

  float acc[8][8];
#pragma unroll
  for (int i = 0; i < 8; ++i)
#pragma unroll
    for (int j = 0; j < 8; ++j) acc[i][j] = 0.f;

  for (int kt = 0; kt < K; kt += BK) {
    float a_reg[8], w_reg[8];
    {
      const float* ap = A + (size_t)(m0 + row) * K + (kt + kh);
      float4 v0 = *(const float4*)ap;
      float4 v1 = *(const float4*)(ap + 4);
      a_reg[0] = v0.x; a_reg[1] = v0.y; a_reg[2] = v0.z; a_reg[3] = v0.w;
      a_reg[4] = v1.x; a_reg[5] = v1.y; a_reg[6] = v1.z; a_reg[7] = v1.w;
    }
    {
      int nn = n0 + row;
      if (nn < N) {
        const float* wp = W + (size_t)nn * K + (kt + kh);
        float4 v0 = *(const float4*)wp;
        float4 v1 = *(const float4*)(wp + 4);
        w_reg[0] = v0.x; w_reg[1] = v0.y; w_reg[2] = v0.z; w_reg[3] = v0.w;
        w_reg[4] = v1.x; w_reg[5] = v1.y; w_reg[6] = v1.z; w_reg[7] = v1.w;
      } else {
#pragma unroll
        for (int q = 0; q < 8; ++q) w_reg[q] = 0.f;
      }
    }
    __syncthreads();
#pragma unroll
    for (int q = 0; q < 8; ++q) { Asm[kh + q][row] = a_reg[q]; Wsm[kh + q][row] = w_reg[q]; }
    __syncthreads();
#pragma unroll
    for (int k = 0; k < BK; ++k) {
      float4 a0 = *(const float4*)&Asm[k][ty * 4];
      float4 a1 = *(const float4*)&Asm[k][ty * 4 + 64];
      float4 b0 = *(const float4*)&Wsm[k][tx * 4];
      float4 b1 = *(const float4*)&Wsm[k][tx * 4 + 64];
      float av[8] = {a0.x, a0.y, a0.z, a0.w, a1.x, a1.y, a1.z, a1.w};
      float bv[8] = {b0.x, b0.y, b0.z, b0.w, b1.x, b1.y, b1.z, b1.w};
#pragma unroll
      for (int i = 0; i < 8; ++i)
#pragma unroll
        for (int j = 0; j < 8; ++j) acc[i][j] += av[i] * bv[j];
    }
  }

#pragma unroll
  for (int ih = 0; ih < 2; ++ih)
#pragma unroll
    for (int i = 0; i < 4; ++i) {
      int m = m0 + ty * 4 + ih * 64 + i;
#pragma unroll
      for (int jh = 0; jh < 2; ++jh) {
        int nn = n0 + tx * 4 + jh * 64;
        if (nn < N) {
          float4 v;
          v.x = acc[ih * 4 + i][jh * 4 + 0] + bias[nn + 0];
          v.y = acc[ih * 4 + i][jh * 4 + 1] + bias[nn + 1];
          v.z = acc[ih * 4 + i][jh * 4 + 2] + bias[nn + 2];
          v.w = acc[ih * 4 + i][jh * 4 + 3] + bias[nn + 3];
          *(float4*)&C[(size_t)m * N + nn] = v;
        }
      }
    }
}

// ---------------------------------------------------------------- MFMA flash rel-attn (bf16 in/out)
#define AST 72
#define VST 74
#define GST 100

__global__ __launch_bounds__(256) void attn_mfma_kernel(
    const ushort* __restrict__ heads, const ushort* __restrict__ rk,
    const float* __restrict__ rwb, const float* __restrict__ rrb,
    ushort* __restrict__ avec)
{
  __shared__ __attribute__((aligned(16))) ushort Qw[32 * AST];
  __shared__ __attribute__((aligned(16))) ushort Qr[48 * AST];
  __shared__ __attribute__((aligned(16))) ushort Ks[64 * AST];
  __shared__ __attribute__((aligned(16))) ushort Vt[64 * VST];
  __shared__ __attribute__((aligned(16))) ushort Re[96 * AST];
  __shared__ __attribute__((aligned(16))) ushort Sb[32 * AST];
  __shared__ __attribute__((aligned(16))) ushort Gb[48 * GST];
  __shared__ __attribute__((aligned(16))) ushort Pb[32 * AST];
  __shared__ float alphaB[32];
  __shared__ float liB[32];

  const int tid  = threadIdx.x;
  const int i0   = blockIdx.x * 32;
  const int b    = blockIdx.y & 1;
  const int n    = blockIdx.y >> 1;
  const int wave = tid >> 6;
  const int lane = tid & 63;
  const int quad = lane >> 4;
  const int lidx = lane & 15;

  for (int e = tid; e < 48 * 64; e += 256) {
    int rr = e >> 6, d = e & 63;
    int ii = i0 + rr;
    float qv = (ii < T_) ? bf2f(heads[(size_t)(ii * B_ + b) * 1536 + n * 64 + d]) : 0.f;
    Qr[rr * AST + d] = f2bf(qv + rrb[n * 64 + d]);
    if (rr < 32) Qw[rr * AST + d] = f2bf(qv + rwb[n * 64 + d]);
  }

  float acc[2][4] = {{0.f, 0.f, 0.f, 0.f}, {0.f, 0.f, 0.f, 0.f}};
  float mi = -INFINITY, li = 0.f;
  const int r  = tid >> 3;
  const int c0 = (tid & 7) * 8;

  for (int jt = 0; jt < 32; ++jt) {
    const int j0 = jt * 64;
    const int qmin = j0 + 2016 - i0;
    __syncthreads();

    // K: pure bf16 copy, 16B chunks
    for (int e = tid; e < 64 * 8; e += 256) {
      int key = e >> 3, c = e & 7;
      *(uint4*)&Ks[key * AST + c * 8] =
          *(const uint4*)&heads[(size_t)((j0 + key) * B_ + b) * 1536 + 512 + n * 64 + c * 8];
    }
    // V transposed: pack key-pairs into dwords
    for (int e = tid; e < 2048; e += 256) {
      int d = e & 63, kp = e >> 6;
      size_t base = (size_t)((j0 + 2 * kp) * B_ + b) * 1536 + 1024 + n * 64 + d;
      uint pk = (uint)heads[base] | ((uint)heads[base + 3072] << 16);
      *(uint*)&Vt[d * VST + 2 * kp] = pk;
    }
    // Rext window: bf16 copy, 8B chunks
    for (int e4 = tid; e4 < 96 * 16; e4 += 256) {
      int rr = e4 >> 4, d4 = (e4 & 15) * 4;
      int qh = qmin + rr;
      uint2 v = {0u, 0u};
      if (qh != T_) {
        int p = (qh < T_) ? qh : qh - T_ - 1;
        v = *(const uint2*)&rk[(size_t)p * DM + n * 64 + d4];
      }
      *(uint2*)&Re[rr * AST + d4] = v;
    }
    __syncthreads();

    // AC tiles
#pragma unroll
    for (int q = 0; q < 2; ++q) {
      int t2 = wave * 2 + q, s = t2 >> 2, ct = t2 & 3;
      float4v c = {0.f, 0.f, 0.f, 0.f};
#pragma unroll
      for (int kb = 0; kb < 2; ++kb) {
        short8 a  = *(const short8*)&Qw[(s * 16 + lidx) * AST + kb * 32 + quad * 8];
        short8 bk = *(const short8*)&Ks[(ct * 16 + lidx) * AST + kb * 32 + quad * 8];
        c = __builtin_amdgcn_mfma_f32_16x16x32_bf16(a, bk, c, 0, 0, 0);
      }
#pragma unroll
      for (int reg = 0; reg < 4; ++reg)
        Sb[(s * 16 + quad * 4 + reg) * AST + ct * 16 + lidx] = f2bf(c[reg]);
    }
    // G tiles
    for (int g = wave; g < 16; g += 4) {
      int sg = (g < 12) ? (g / 6) : 2;
      int ct = (g < 12) ? (g % 6) : (g - 12);
      float4v c = {0.f, 0.f, 0.f, 0.f};
#pragma unroll
      for (int kb = 0; kb < 2; ++kb) {
        short8 a  = *(const short8*)&Qr[(sg * 16 + lidx) * AST + kb * 32 + quad * 8];
        short8 br = *(const short8*)&Re[(ct * 16 + lidx) * AST + kb * 32 + quad * 8];
        c = __builtin_amdgcn_mfma_f32_16x16x32_bf16(a, br, c, 0, 0, 0);
      }
#pragma unroll
      for (int reg = 0; reg < 4; ++reg)
        Gb[(sg * 16 + quad * 4 + reg) * GST + ct * 16 + lidx] = f2bf(c[reg]);
    }
    __syncthreads();

    // online softmax
    {
      short8 sv = *(const short8*)&Sb[r * AST + c0];
      float x[8];
#pragma unroll
      for (int k = 0; k < 8; ++k) {
        int w  = c0 + k + 31 - r;
        int qh = qmin + w;
        int sel = (qh > T_) ? 1 : 0;
        float bd = bf2f(Gb[(r + sel) * GST + w]);
        x[k] = (bf2f((ushort)sv[k]) + bd) * 0.125f;
      }
      float lm = x[0];
#pragma unroll
      for (int k = 1; k < 8; ++k) lm = fmaxf(lm, x[k]);
      lm = fmaxf(lm, __shfl_xor(lm, 1));
      lm = fmaxf(lm, __shfl_xor(lm, 2));
      lm = fmaxf(lm, __shfl_xor(lm, 4));
      float mnew = fmaxf(mi, lm);
      float al = __expf(mi - mnew);
      float ls = 0.f;
      short8 pv8;
#pragma unroll
      for (int k = 0; k < 8; ++k) {
        float p = __expf(x[k] - mnew);
        ls += p;
        ((ushort*)&pv8)[k] = f2bf(p);
      }
      ls += __shfl_xor(ls, 1);
      ls += __shfl_xor(ls, 2);
      ls += __shfl_xor(ls, 4);
      li = li * al + ls;
      mi = mnew;
      *(short8*)&Pb[r * AST + c0] = pv8;
      if ((tid & 7) == 0) alphaB[r] = al;
    }
    __syncthreads();

    // PV
#pragma unroll
    for (int q = 0; q < 2; ++q) {
      int t2 = wave * 2 + q, s = t2 >> 2, dt = t2 & 3;
      float4v c;
#pragma unroll
      for (int reg = 0; reg < 4; ++reg)
        c[reg] = acc[q][reg] * alphaB[s * 16 + quad * 4 + reg];
#pragma unroll
      for (int kb = 0; kb < 2; ++kb) {
        short8 a = *(const short8*)&Pb[(s * 16 + lidx) * AST + kb * 32 + quad * 8];
        union { short8 v; uint u[4]; } bv;
        const uint* vp = (const uint*)&Vt[(dt * 16 + lidx) * VST + kb * 32 + quad * 8];
        bv.u[0] = vp[0]; bv.u[1] = vp[1]; bv.u[2] = vp[2]; bv.u[3] = vp[3];
        c = __builtin_amdgcn_mfma_f32_16x16x32_bf16(a, bv.v, c, 0, 0, 0);
      }
#pragma unroll
      for (int reg = 0; reg < 4; ++reg) acc[q][reg] = c[reg];
    }
  }

  if ((tid & 7) == 0) liB[r] = li;
  __syncthreads();
#pragma unroll
  for (int q = 0; q < 2; ++q) {
    int t2 = wave * 2 + q, s = t2 >> 2, dt = t2 & 3;
#pragma unroll
    for (int reg = 0; reg < 4; ++reg) {
      int row = s * 16 + quad * 4 + reg;
      float val = acc[q][reg] / liB[row];
      int i = i0 + row;
      avec[(size_t)(i * B_ + b) * DM + n * 64 + dt * 16 + lidx] = f2bf(val);
    }
  }
}

// ---------------------------------------------------------------- LN(residual), dual out
__global__ __launch_bounds__(256) void ln_res_kernel(
    float* __restrict__ h, ushort* __restrict__ hb, const float* __restrict__ delta,
    const float* __restrict__ s, const float* __restrict__ bb)
{
  const int m = blockIdx.x;
  const int tid = threadIdx.x;
  float* hp = h + (size_t)m * DM;
  ushort* hbp = hb + (size_t)m * DM;
  const float* dp = delta + (size_t)m * DM;
  float x0 = hp[tid] + dp[tid];
  float x1 = hp[tid + 256] + dp[tid + 256];
  float sum = x0 + x1, sq = x0 * x0 + x1 * x1;
#pragma unroll
  for (int o = 32; o > 0; o >>= 1) { sum += __shfl_down(sum, o); sq += __shfl_down(sq, o); }
  __shared__ float part[8];
  int wv = tid >> 6;
  if ((tid & 63) == 0) { part[wv * 2] = sum; part[wv * 2 + 1] = sq; }
  __syncthreads();
  float ts = part[0] + part[2] + part[4] + part[6];
  float tq = part[1] + part[3] + part[5] + part[7];
  float mu = ts * (1.f / DM);
  float var = tq * (1.f / DM) - mu * mu;
  float rs = rsqrtf(var + 1e-5f);
  float y0 = (x0 - mu) * rs * s[tid]       + bb[tid];
  float y1 = (x1 - mu) * rs * s[tid + 256] + bb[tid + 256];
  hp[tid] = y0;       hbp[tid] = f2bf(y0);
  hp[tid + 256] = y1; hbp[tid + 256] = f2bf(y1);
}

// ---------------------------------------------------------------- classifier reorder
__global__ __launch_bounds__(256) void reorder_kernel(const float* __restrict__ ct,
                                                      float* __restrict__ out) {
  int idx = blockIdx.x * 256 + threadIdx.x;
  if (idx >= B_ * NCLS * T_) return;
  int t  = idx & (T_ - 1);
  int nc = (idx >> 11) & 63;
  int bb = idx >> 17;
  out[idx] = ct[(size_t)(t * B_ + bb) * NCLS + nc];
}

// ---------------------------------------------------------------- launch
extern "C" void kernel_launch(void* const* d_in, const int* in_sizes, int n_in,
                              void* d_out, int out_size, void* d_ws, size_t ws_size,
                              hipStream_t stream)
{
  const float* x     = (const float*)d_in[0];
  const float* emb_w = (const float*)d_in[1];
  const float* emb_b = (const float*)d_in[2];
  const float* rwb   = (const float*)d_in[3];
  const float* rrb   = (const float*)d_in[4];
  const float* qkv_w = (const float*)d_in[5];
  const float* qkv_b = (const float*)d_in[6];
  const float* rproj = (const float*)d_in[7];
  const float* o_w   = (const float*)d_in[8];
  const float* ln1s  = (const float*)d_in[9];
  const float* ln1b  = (const float*)d_in[10];
  const float* ff1w  = (const float*)d_in[11];
  const float* ff1b  = (const float*)d_in[12];
  const float* ff2w  = (const float*)d_in[13];
  const float* ff2b  = (const float*)d_in[14];
  const float* ln2s  = (const float*)d_in[15];
  const float* ln2b  = (const float*)d_in[16];
  const float* clsw  = (const float*)d_in[17];
  const float* clsb  = (const float*)d_in[18];
  float* out = (float*)d_out;

  char* p = (char*)d_ws;
  float*  h       = (float*)p;   p += (size_t)MT * DM * 4;        // 8 MB
  float*  tmpf    = (float*)p;   p += (size_t)MT * DM * 4;        // 8 MB
  ushort* hb      = (ushort*)p;  p += (size_t)MT * DM * 2;        // 4 MB
  ushort* headsb  = (ushort*)p;  p += (size_t)MT * 1536 * 2;      // 12 MB
  ushort* peb     = (ushort*)p;  p += (size_t)T_ * DM * 2;        // 2 MB
  ushort* rkb     = (ushort*)p;  p += (size_t)T_ * DM * 2;        // 2 MB
  ushort* avecb   = (ushort*)p;  p += (size_t)MT * DM * 2;        // 4 MB
  ushort* xfb     = (ushort*)p;  p += (size_t)MT * INCH * 2;      // 16 MB (xb, later ffb)
  ushort* emb_wb  = (ushort*)p;  p += (size_t)DM * INCH * 2;      // 2 MB
  ushort* qkv_wb  = (ushort*)p;  p += (size_t)4 * 1536 * DM * 2;  // 6 MB
  ushort* rproj_wb= (ushort*)p;  p += (size_t)4 * DM * DM * 2;    // 2 MB
  ushort* o_wb    = (ushort*)p;  p += (size_t)4 * DM * DM * 2;    // 2 MB
  ushort* ff1_wb  = (ushort*)p;  p += (size_t)4 * DI * DM * 2;    // 8 MB
  ushort* ff2_wb  = (ushort*)p;  p += (size_t)4 * DM * DI * 2;    // 8 MB

  // weight conversions + pos emb + x transpose
  cvt_kernel<<<(DM * INCH / 4 + 255) / 256, 256, 0, stream>>>(emb_w, emb_wb, DM * INCH / 4);
  cvt_kernel<<<(4 * 1536 * DM / 4 + 255) / 256, 256, 0, stream>>>(qkv_w, qkv_wb, 4 * 1536 * DM / 4);
  cvt_kernel<<<(4 * DM * DM / 4 + 255) / 256, 256, 0, stream>>>(rproj, rproj_wb, 4 * DM * DM / 4);
  cvt_kernel<<<(4 * DM * DM / 4 + 255) / 256, 256, 0, stream>>>(o_w, o_wb, 4 * DM * DM / 4);
  cvt_kernel<<<(4 * DI * DM / 4 + 255) / 256, 256, 0, stream>>>(ff1w, ff1_wb, 4 * DI * DM / 4);
  cvt_kernel<<<(4 * DM * DI / 4 + 255) / 256, 256, 0, stream>>>(ff2w, ff2_wb, 4 * DM * DI / 4);
  pos_kernel<<<(T_ * DM) / 256, 256, 0, stream>>>(peb);
  xpose_kernel<<<dim3(T_ / 32, INCH / 32, B_), 256, 0, stream>>>(x, xfb);

  // embed: h fp32 + hb bf16
  gemm_bf16<2, false><<<dim3(DM / 128, MT / 128), 256, 0, stream>>>(
      xfb, emb_wb, emb_b, h, hb, MT, DM, INCH);

  for (int l = 0; l < 4; ++l) {
    gemm_bf16<1, false><<<dim3(1536 / 128, MT / 128), 256, 0, stream>>>(
        hb, qkv_wb + (size_t)l * 1536 * DM, qkv_b + l * 1536, nullptr, headsb, MT, 1536, DM);
    gemm_bf16<1, false><<<dim3(DM / 128, T_ / 128), 256, 0, stream>>>(
        peb, rproj_wb + (size_t)l * DM * DM, nullptr, nullptr, rkb, T_, DM, DM);
    attn_mfma_kernel<<<dim3(T_ / 32, B_ * NH), 256, 0, stream>>>(headsb, rkb, rwb, rrb, avecb);
    gemm_bf16<0, false><<<dim3(DM / 128, MT / 128), 256, 0, stream>>>(
        avecb, o_wb + (size_t)l * DM * DM, nullptr, tmpf, nullptr, MT, DM, DM);
    ln_res_kernel<<<MT, 256, 0, stream>>>(h, hb, tmpf, ln1s + l * DM, ln1b + l * DM);
    gemm_bf16<1, true><<<dim3(DI / 128, MT / 128), 256, 0, stream>>>(
        hb, ff1_wb + (size_t)l * DI * DM, ff1b + l * DI, nullptr, xfb, MT, DI, DM);
    gemm_bf16<0, false><<<dim3(DM / 128, MT / 128), 256, 0, stream>>>(
        xfb, ff2_wb + (size_t)l * DM * DI, ff2b + l * DM, tmpf, nullptr, MT, DM, DI);
    ln_res_kernel<<<MT, 256, 0, stream>>>(h, hb, tmpf, ln2s + l * DM, ln2b + l * DM);
  }

  gemm_f32<<<dim3(1, MT / BM), 256, 0, stream>>>(h, clsw, clsb, tmpf, MT, NCLS, DM);
  reorder_kernel<<<(B_ * NCLS * T_) / 256, 256, 0, stream>>>(tmpf, out);
}

// Round 4
// 1174.761 us; speedup vs baseline: 9.9132x; 1.8043x over previous
//
#include <hip/hip_runtime.h>
#include <hip/hip_bf16.h>
#include <math.h>

// TransformerXL forward. bf16-MFMA GEMMs + register-resident flash rel-attention.
// Layout: [t,b,*] flattened, m = t*B_ + b.

#define T_   2048
#define B_   2
#define DM   512
#define NH   8
#define DH   64
#define DI   2048
#define INCH 2048
#define NCLS 64
#define MT   4096   // T_*B_

typedef __attribute__((ext_vector_type(8))) short short8;
typedef __attribute__((ext_vector_type(4))) float float4v;

__device__ inline ushort f2bf(float f) {
  uint u = __float_as_uint(f);
  return (ushort)((u + 0x7FFFu + ((u >> 16) & 1u)) >> 16);   // RNE
}
__device__ inline float bf2f(ushort h) { return __uint_as_float(((uint)h) << 16); }
__device__ inline uint pkbf(float a, float b) {
  __hip_bfloat162 h = __float22bfloat162_rn(float2{a, b});
  return *(uint*)&h;
}
__device__ inline void gload16(const void* g, void* lds) {
  __builtin_amdgcn_global_load_lds(
      (const __attribute__((address_space(1))) void*)g,
      (__attribute__((address_space(3))) void*)lds, 16, 0, 0);
}

// ---------------------------------------------------------------- pos emb (bf16 out)
__global__ __launch_bounds__(256) void pos_kernel(ushort* __restrict__ pe) {
  int idx = blockIdx.x * 256 + threadIdx.x;
  if (idx >= T_ * DM) return;
  int t = idx >> 9;
  int i = idx & 511;
  int j = (i < 256) ? i : (i - 256);
  double invf = exp(-(double)(2 * j) * (9.210340371976184 / 512.0));
  double a = (double)(T_ - 1 - t) * invf;
  pe[idx] = f2bf((i < 256) ? (float)sin(a) : (float)cos(a));
}

// ---------------------------------------------------------------- fp32 -> bf16 convert
__global__ __launch_bounds__(256) void cvt_kernel(const float* __restrict__ src,
                                                  ushort* __restrict__ dst, int n4) {
  int i = blockIdx.x * 256 + threadIdx.x;
  if (i >= n4) return;
  float4 v = ((const float4*)src)[i];
  ushort4 w = { f2bf(v.x), f2bf(v.y), f2bf(v.z), f2bf(v.w) };
  ((ushort4*)dst)[i] = w;
}

// ---------------------------------------------------------------- x[B,C,T] -> xb[(t*2+b), C] bf16
__global__ __launch_bounds__(256) void xpose_kernel(const float* __restrict__ x,
                                                    ushort* __restrict__ xb) {
  __shared__ float s[32][33];
  int t0 = blockIdx.x * 32, k0 = blockIdx.y * 32, b = blockIdx.z;
  int tx = threadIdx.x & 31, ty = threadIdx.x >> 5;
#pragma unroll
  for (int l = 0; l < 4; ++l) {
    int k = k0 + ty + l * 8;
    s[ty + l * 8][tx] = x[((size_t)b * INCH + k) * T_ + t0 + tx];
  }
  __syncthreads();
#pragma unroll
  for (int l = 0; l < 4; ++l) {
    int t = t0 + ty + l * 8;
    xb[((size_t)(t * 2 + b)) * INCH + k0 + tx] = f2bf(s[tx][ty + l * 8]);
  }
}

// ---------------------------------------------------------------- bf16 MFMA GEMM
// C[m,n] = act( sum_k A[m,k]*W[n,k] + bias[n] ). A[M,K], W[N,K] bf16 row-major.
// TM in {64,128}. OUTMODE: 0 fp32, 1 bf16, 2 both.
template<int TM, int OUTMODE, bool RELU>
__global__ __launch_bounds__(256) void gemm_bf16(
    const ushort* __restrict__ A, const ushort* __restrict__ W,
    const float* __restrict__ bias, float* __restrict__ Cf, ushort* __restrict__ Cb,
    int M, int N, int K)
{
  __shared__ __attribute__((aligned(16))) ushort As[TM * 32];
  __shared__ __attribute__((aligned(16))) ushort Bs[128 * 32];
  const int NI = TM / 32;
  const int tid  = threadIdx.x;
  const int wave = tid >> 6, lane = tid & 63;
  const int quad = lane >> 4, lidx = lane & 15;
  const int m0 = blockIdx.y * TM, n0 = blockIdx.x * 128;
  const int srow  = lane >> 2;
  const int selem = (lane & 3) * 8;

  float4v acc[NI * 4];
#pragma unroll
  for (int i = 0; i < NI * 4; ++i) acc[i] = (float4v){0.f, 0.f, 0.f, 0.f};

  const int wm = (wave >> 1) * (TM / 2), wn = (wave & 1) * 64;

  for (int k0 = 0; k0 < K; k0 += 32) {
    __syncthreads();
#pragma unroll
    for (int h = 0; h < TM / 64; ++h) {
      const ushort* ga = A + (size_t)(m0 + h * 64 + wave * 16 + srow) * K + k0 + selem;
      gload16(ga, &As[(h * 64 + wave * 16) * 32]);
    }
    const ushort* gb0 = W + (size_t)(n0 + wave * 16 + srow) * K + k0 + selem;
    gload16(gb0,                  &Bs[wave * 512]);
    gload16(gb0 + (size_t)64 * K, &Bs[2048 + wave * 512]);
    __syncthreads();

    short8 af[NI], bf[4];
#pragma unroll
    for (int i = 0; i < NI; ++i) af[i] = *(const short8*)&As[(wm + i * 16 + lidx) * 32 + quad * 8];
#pragma unroll
    for (int j = 0; j < 4; ++j) bf[j] = *(const short8*)&Bs[(wn + j * 16 + lidx) * 32 + quad * 8];
#pragma unroll
    for (int i = 0; i < NI; ++i)
#pragma unroll
      for (int j = 0; j < 4; ++j)
        acc[i * 4 + j] = __builtin_amdgcn_mfma_f32_16x16x32_bf16(af[i], bf[j], acc[i * 4 + j], 0, 0, 0);
  }

  float bj[4];
#pragma unroll
  for (int j = 0; j < 4; ++j) bj[j] = bias ? bias[n0 + wn + j * 16 + lidx] : 0.f;
#pragma unroll
  for (int i = 0; i < NI; ++i) {
    int rbase = m0 + wm + i * 16 + quad * 4;
#pragma unroll
    for (int j = 0; j < 4; ++j) {
      int col = n0 + wn + j * 16 + lidx;
#pragma unroll
      for (int reg = 0; reg < 4; ++reg) {
        float v = acc[i * 4 + j][reg] + bj[j];
        if (RELU) v = fmaxf(v, 0.f);
        size_t off = (size_t)(rbase + reg) * N + col;
        if (OUTMODE != 1) Cf[off] = v;
        if (OUTMODE != 0) Cb[off] = f2bf(v);
      }
    }
  }
}

// ---------------------------------------------------------------- fp32 GEMM (cls only)
#define BM 128
#define BN 128
#define BK 16
#define LDT 132

__global__ __launch_bounds__(256) void gemm_f32(
    const float* __restrict__ A, const float* __restrict__ W,
    const float* __restrict__ bias, float* __restrict__ C,
    int M, int N, int K)
{
  __shared__ float Asm[BK][LDT];
  __shared__ float Wsm[BK][LDT];
  const int tid = threadIdx.x;
  const int m0 = blockIdx.y * BM;
  const int n0 = blockIdx.x * BN;
  const int row = tid >> 1;
  const int kh  = (tid & 1) * 8;
  const int ty  = tid >> 4;
  const int tx  = tid & 15;

  float acc[8][8];
#pragma unroll
  for (int i = 0; i < 8; ++i)
#pragma unroll
    for (int j = 0; j < 8; ++j) acc[i][j] = 0.f;

  for (int kt = 0; kt < K; kt += BK) {
    float a_reg[8], w_reg[8];
    {
      const float* ap = A + (size_t)(m0 + row) * K + (kt + kh);
      float4 v0 = *(const float4*)ap;
      float4 v1 = *(const float4*)(ap + 4);
      a_reg[0] = v0.x; a_reg[1] = v0.y; a_reg[2] = v0.z; a_reg[3] = v0.w;
      a_reg[4] = v1.x; a_reg[5] = v1.y; a_reg[6] = v1.z; a_reg[7] = v1.w;
    }
    {
      int nn = n0 + row;
      if (nn < N) {
        const float* wp = W + (size_t)nn * K + (kt + kh);
        float4 v0 = *(const float4*)wp;
        float4 v1 = *(const float4*)(wp + 4);
        w_reg[0] = v0.x; w_reg[1] = v0.y; w_reg[2] = v0.z; w_reg[3] = v0.w;
        w_reg[4] = v1.x; w_reg[5] = v1.y; w_reg[6] = v1.z; w_reg[7] = v1.w;
      } else {
#pragma unroll
        for (int q = 0; q < 8; ++q) w_reg[q] = 0.f;
      }
    }
    __syncthreads();
#pragma unroll
    for (int q = 0; q < 8; ++q) { Asm[kh + q][row] = a_reg[q]; Wsm[kh + q][row] = w_reg[q]; }
    __syncthreads();
#pragma unroll
    for (int k = 0; k < BK; ++k) {
      float4 a0 = *(const float4*)&Asm[k][ty * 4];
      float4 a1 = *(const float4*)&Asm[k][ty * 4 + 64];
      float4 b0 = *(const float4*)&Wsm[k][tx * 4];
      float4 b1 = *(const float4*)&Wsm[k][tx * 4 + 64];
      float av[8] = {a0.x, a0.y, a0.z, a0.w, a1.x, a1.y, a1.z, a1.w};
      float bv[8] = {b0.x, b0.y, b0.z, b0.w, b1.x, b1.y, b1.z, b1.w};
#pragma unroll
      for (int i = 0; i < 8; ++i)
#pragma unroll
        for (int j = 0; j < 8; ++j) acc[i][j] += av[i] * bv[j];
    }
  }

#pragma unroll
  for (int ih = 0; ih < 2; ++ih)
#pragma unroll
    for (int i = 0; i < 4; ++i) {
      int m = m0 + ty * 4 + ih * 64 + i;
#pragma unroll
      for (int jh = 0; jh < 2; ++jh) {
        int nn = n0 + tx * 4 + jh * 64;
        if (nn < N) {
          float4 v;
          v.x = acc[ih * 4 + i][jh * 4 + 0] + bias[nn + 0];
          v.y = acc[ih * 4 + i][jh * 4 + 1] + bias[nn + 1];
          v.z = acc[ih * 4 + i][jh * 4 + 2] + bias[nn + 2];
          v.w = acc[ih * 4 + i][jh * 4 + 3] + bias[nn + 3];
          *(float4*)&C[(size_t)m * N + nn] = v;
        }
      }
    }
}

// ---------------------------------------------------------------- MFMA flash rel-attn
// Block: 64 query rows of one (b,n); wave w owns 16-row strip. Key tiles of 64.
// rel_shift (no mask) wraps: BD[i,j] = Qr[r+sel].Rext[qh], qh = qmin+w,
// w = c+63-r, sel = qh>T; Rext[qh<T]=rk[qh], Rext[T]=0, Rext[qh>T]=rk[qh-T-1].
// G stored transposed Gbt[w][grow]; S register-resident; softmax within-wave.
#define VST 72    // Vt ushort stride
#define GT  66    // Gbt grow stride

__global__ __launch_bounds__(256) void attn_mfma_kernel(
    const ushort* __restrict__ heads, const ushort* __restrict__ rk,
    const float* __restrict__ rwb, const float* __restrict__ rrb,
    ushort* __restrict__ avec)
{
  __shared__ __attribute__((aligned(16))) ushort Ks[64 * 64];    // swizzled
  __shared__ __attribute__((aligned(16))) ushort Vt[64 * VST];   // [d][key]
  __shared__ __attribute__((aligned(16))) ushort Re[128 * 64];   // swizzled, [w][d]
  __shared__ __attribute__((aligned(16))) ushort Gbt[128 * GT];  // [w][grow] bf16
  __shared__ __attribute__((aligned(16))) ushort Pb[64 * 64];    // swizzled, [row][key]

  const int tid  = threadIdx.x;
  const int i0   = blockIdx.x * 64;
  const int b    = blockIdx.y & 1;
  const int n    = blockIdx.y >> 1;
  const int wv   = tid >> 6;
  const int lane = tid & 63;
  const int quad = lane >> 4;
  const int lidx = lane & 15;

  // swizzled fragment byte offsets (within a 16-row x 128B region)
  const int swoff0 = lidx * 128 + ((quad ^ (lidx & 7)) * 16);
  const int swoff1 = lidx * 128 + (((4 + quad) ^ (lidx & 7)) * 16);

  // ---- Q fragments in registers (A-operand layout: row=lidx, k=quad*8+j)
  short8 qw0, qw1, qr0, qr1, q40, q41;
  {
    auto qfrag = [&](int row, int kb, const float* bias) -> short8 {
      short8 q;
      if (row < T_) q = *(const short8*)&heads[(size_t)(row * 2 + b) * 1536 + n * 64 + kb * 32 + quad * 8];
      else { for (int t = 0; t < 8; ++t) ((ushort*)&q)[t] = 0; }
      short8 o;
#pragma unroll
      for (int t = 0; t < 8; ++t) {
        float f = bf2f((ushort)((ushort*)&q)[t]) + bias[n * 64 + kb * 32 + quad * 8 + t];
        ((ushort*)&o)[t] = f2bf(f);
      }
      return o;
    };
    int rown = i0 + 16 * wv + lidx;
    qw0 = qfrag(rown, 0, rwb); qw1 = qfrag(rown, 1, rwb);
    qr0 = qfrag(rown, 0, rrb); qr1 = qfrag(rown, 1, rrb);
    int row4 = i0 + 64 + lidx;
    q40 = qfrag(row4, 0, rrb); q41 = qfrag(row4, 1, rrb);
  }

  float4v oacc[4];
#pragma unroll
  for (int d = 0; d < 4; ++d) oacc[d] = (float4v){0.f, 0.f, 0.f, 0.f};
  float mi[4] = {-INFINITY, -INFINITY, -INFINITY, -INFINITY};
  float li[4] = {0.f, 0.f, 0.f, 0.f};
  float al[4];

  const int rbase = 16 * wv + quad * 4;

  for (int jt = 0; jt < 32; ++jt) {
    const int j0 = jt * 64;
    const int qmin = j0 + 1984 - i0;
    __syncthreads();   // prev iter's PV / gather complete

    // ---- stage K via global_load_lds (swizzled rows)
    {
      int c = (lane & 7) ^ ((lane >> 3) & 7);
#pragma unroll
      for (int half = 0; half < 2; ++half) {
        int r0 = 8 * wv + 32 * half;
        const ushort* g = heads + (size_t)((j0 + r0 + (lane >> 3)) * 2 + b) * 1536 + 512 + n * 64 + c * 8;
        gload16(g, &Ks[r0 * 64]);
      }
      // ---- stage Rext window (128 rows) with wrap, via global_load_lds
#pragma unroll
      for (int q4 = 0; q4 < 4; ++q4) {
        int r0 = 8 * wv + 32 * q4;
        int w  = r0 + (lane >> 3);
        int qh = qmin + w;
        int p  = (qh > T_) ? (qh - T_ - 1) : ((qh == T_) ? 0 : qh);
        const ushort* g = rk + (size_t)p * 512 + n * 64 + c * 8;
        gload16(g, &Re[r0 * 64]);
      }
    }
    // ---- stage V transposed (pack key-pairs into dwords)
    {
      int kp = tid >> 3, dc = tid & 7;
      const ushort* vp = heads + (size_t)((j0 + 2 * kp) * 2 + b) * 1536 + 1024 + n * 64 + dc * 8;
      uint4 a  = *(const uint4*)vp;
      uint4 bq = *(const uint4*)(vp + 3072);
      uint pr[8];
      pr[0] = (a.x & 0xFFFFu) | (bq.x << 16);  pr[1] = (a.x >> 16) | (bq.x & 0xFFFF0000u);
      pr[2] = (a.y & 0xFFFFu) | (bq.y << 16);  pr[3] = (a.y >> 16) | (bq.y & 0xFFFF0000u);
      pr[4] = (a.z & 0xFFFFu) | (bq.z << 16);  pr[5] = (a.z >> 16) | (bq.z & 0xFFFF0000u);
      pr[6] = (a.w & 0xFFFFu) | (bq.w << 16);  pr[7] = (a.w >> 16) | (bq.w & 0xFFFF0000u);
      uint* dst = (uint*)Vt;
#pragma unroll
      for (int q = 0; q < 8; ++q)
        dst[(size_t)(dc * 8 + q) * (VST / 2) + kp] = pr[q];
    }
    __syncthreads();
    // zero-row fixup (Rext[T] = 0)
    {
      int Tidx = T_ - qmin;
      if (Tidx >= 0 && Tidx < 128) {
        if (tid < 32) ((uint*)Re)[Tidx * 32 + tid] = 0u;
        __syncthreads();
      }
    }

    // ---- AC: S[strip][64] in registers
    float4v sv[4];
#pragma unroll
    for (int ct = 0; ct < 4; ++ct) {
      float4v c = {0.f, 0.f, 0.f, 0.f};
      short8 b0 = *(const short8*)((const char*)Ks + ct * 2048 + swoff0);
      short8 b1 = *(const short8*)((const char*)Ks + ct * 2048 + swoff1);
      c = __builtin_amdgcn_mfma_f32_16x16x32_bf16(qw0, b0, c, 0, 0, 0);
      c = __builtin_amdgcn_mfma_f32_16x16x32_bf16(qw1, b1, c, 0, 0, 0);
      sv[ct] = c;
    }
    // ---- G tiles -> Gbt[w][grow] (transposed store, packed writes)
    {
      int ws = 48 - 16 * wv;
#pragma unroll
      for (int tt = 0; tt < 5; ++tt) {
        int w0 = ws + 16 * tt;
        float4v g = {0.f, 0.f, 0.f, 0.f};
        short8 b0 = *(const short8*)((const char*)Re + w0 * 128 + swoff0);
        short8 b1 = *(const short8*)((const char*)Re + w0 * 128 + swoff1);
        g = __builtin_amdgcn_mfma_f32_16x16x32_bf16(qr0, b0, g, 0, 0, 0);
        g = __builtin_amdgcn_mfma_f32_16x16x32_bf16(qr1, b1, g, 0, 0, 0);
        uint idx = ((w0 + lidx) * GT + 16 * wv + quad * 4) >> 1;
        ((uint*)Gbt)[idx]     = pkbf(g[0], g[1]);
        ((uint*)Gbt)[idx + 1] = pkbf(g[2], g[3]);
      }
      // strip 4 (grow = 64 only)
      {
        int w0 = 16 * wv;
        float4v g = {0.f, 0.f, 0.f, 0.f};
        short8 b0 = *(const short8*)((const char*)Re + w0 * 128 + swoff0);
        short8 b1 = *(const short8*)((const char*)Re + w0 * 128 + swoff1);
        g = __builtin_amdgcn_mfma_f32_16x16x32_bf16(q40, b0, g, 0, 0, 0);
        g = __builtin_amdgcn_mfma_f32_16x16x32_bf16(q41, b1, g, 0, 0, 0);
        if (quad == 0) {
          uint idx = ((w0 + lidx) * GT + 64) >> 1;
          ((uint*)Gbt)[idx] = pkbf(g[0], g[1]);
        }
      }
    }
    __syncthreads();

    // ---- gather BD + online softmax (within-wave rows)
    {
      float x[4][4];
#pragma unroll
      for (int reg = 0; reg < 4; ++reg) {
        int rloc = rbase + reg;
#pragma unroll
        for (int ct = 0; ct < 4; ++ct) {
          int w = ct * 16 + lidx + 63 - rloc;
          int sel = (qmin + w > T_) ? 1 : 0;
          float g = bf2f(Gbt[w * GT + rloc + sel]);
          x[ct][reg] = (sv[ct][reg] + g) * 0.125f;
        }
      }
#pragma unroll
      for (int reg = 0; reg < 4; ++reg) {
        int rloc = rbase + reg;
        float m = fmaxf(fmaxf(x[0][reg], x[1][reg]), fmaxf(x[2][reg], x[3][reg]));
        m = fmaxf(m, __shfl_xor(m, 1));
        m = fmaxf(m, __shfl_xor(m, 2));
        m = fmaxf(m, __shfl_xor(m, 4));
        m = fmaxf(m, __shfl_xor(m, 8));
        float mnew = fmaxf(mi[reg], m);
        al[reg] = __expf(mi[reg] - mnew);
        float ls = 0.f;
        int r7 = rloc & 7;
#pragma unroll
        for (int ct = 0; ct < 4; ++ct) {
          float pv = __expf(x[ct][reg] - mnew);
          ls += pv;
          int col = ct * 16 + lidx;
          int scc = (col >> 3) ^ r7;
          Pb[rloc * 64 + scc * 8 + (col & 7)] = f2bf(pv);
        }
        ls += __shfl_xor(ls, 1);
        ls += __shfl_xor(ls, 2);
        ls += __shfl_xor(ls, 4);
        ls += __shfl_xor(ls, 8);
        li[reg] = li[reg] * al[reg] + ls;
        mi[reg] = mnew;
      }
    }
    __syncthreads();

    // ---- PV: O strip += P . V
    {
      short8 pa0 = *(const short8*)((const char*)Pb + 16 * wv * 128 + swoff0);
      short8 pa1 = *(const short8*)((const char*)Pb + 16 * wv * 128 + swoff1);
#pragma unroll
      for (int dt = 0; dt < 4; ++dt) {
        float4v c;
#pragma unroll
        for (int reg = 0; reg < 4; ++reg) c[reg] = oacc[dt][reg] * al[reg];
        const ushort* vb = &Vt[(size_t)(dt * 16 + lidx) * VST];
        short8 vb0 = *(const short8*)(vb + quad * 8);
        short8 vb1 = *(const short8*)(vb + 32 + quad * 8);
        c = __builtin_amdgcn_mfma_f32_16x16x32_bf16(pa0, vb0, c, 0, 0, 0);
        c = __builtin_amdgcn_mfma_f32_16x16x32_bf16(pa1, vb1, c, 0, 0, 0);
        oacc[dt] = c;
      }
    }
  }

  // ---- epilogue
#pragma unroll
  for (int dt = 0; dt < 4; ++dt) {
#pragma unroll
    for (int reg = 0; reg < 4; ++reg) {
      int i = i0 + rbase + reg;
      float val = oacc[dt][reg] / li[reg];
      avec[(size_t)(i * 2 + b) * DM + n * 64 + dt * 16 + lidx] = f2bf(val);
    }
  }
}

// ---------------------------------------------------------------- LN(residual), dual out
__global__ __launch_bounds__(256) void ln_res_kernel(
    float* __restrict__ h, ushort* __restrict__ hb, const float* __restrict__ delta,
    const float* __restrict__ s, const float* __restrict__ bb)
{
  const int m = blockIdx.x;
  const int tid = threadIdx.x;
  float* hp = h + (size_t)m * DM;
  ushort* hbp = hb + (size_t)m * DM;
  const float* dp = delta + (size_t)m * DM;
  float x0 = hp[tid] + dp[tid];
  float x1 = hp[tid + 256] + dp[tid + 256];
  float sum = x0 + x1, sq = x0 * x0 + x1 * x1;
#pragma unroll
  for (int o = 32; o > 0; o >>= 1) { sum += __shfl_down(sum, o); sq += __shfl_down(sq, o); }
  __shared__ float part[8];
  int wv = tid >> 6;
  if ((tid & 63) == 0) { part[wv * 2] = sum; part[wv * 2 + 1] = sq; }
  __syncthreads();
  float ts = part[0] + part[2] + part[4] + part[6];
  float tq = part[1] + part[3] + part[5] + part[7];
  float mu = ts * (1.f / DM);
  float var = tq * (1.f / DM) - mu * mu;
  float rs = rsqrtf(var + 1e-5f);
  float y0 = (x0 - mu) * rs * s[tid]       + bb[tid];
  float y1 = (x1 - mu) * rs * s[tid + 256] + bb[tid + 256];
  hp[tid] = y0;       hbp[tid] = f2bf(y0);
  hp[tid + 256] = y1; hbp[tid + 256] = f2bf(y1);
}

// ---------------------------------------------------------------- classifier reorder
__global__ __launch_bounds__(256) void reorder_kernel(const float* __restrict__ ct,
                                                      float* __restrict__ out) {
  int idx = blockIdx.x * 256 + threadIdx.x;
  if (idx >= B_ * NCLS * T_) return;
  int t  = idx & (T_ - 1);
  int nc = (idx >> 11) & 63;
  int bb = idx >> 17;
  out[idx] = ct[(size_t)(t * B_ + bb) * NCLS + nc];
}

// ---------------------------------------------------------------- launch
extern "C" void kernel_launch(void* const* d_in, const int* in_sizes, int n_in,
                              void* d_out, int out_size, void* d_ws, size_t ws_size,
                              hipStream_t stream)
{
  const float* x     = (const float*)d_in[0];
  const float* emb_w = (const float*)d_in[1];
  const float* emb_b = (const float*)d_in[2];
  const float* rwb   = (const float*)d_in[3];
  const float* rrb   = (const float*)d_in[4];
  const float* qkv_w = (const float*)d_in[5];
  const float* qkv_b = (const float*)d_in[6];
  const float* rproj = (const float*)d_in[7];
  const float* o_w   = (const float*)d_in[8];
  const float* ln1s  = (const float*)d_in[9];
  const float* ln1b  = (const float*)d_in[10];
  const float* ff1w  = (const float*)d_in[11];
  const float* ff1b  = (const float*)d_in[12];
  const float* ff2w  = (const float*)d_in[13];
  const float* ff2b  = (const float*)d_in[14];
  const float* ln2s  = (const float*)d_in[15];
  const float* ln2b  = (const float*)d_in[16];
  const float* clsw  = (const float*)d_in[17];
  const float* clsb  = (const float*)d_in[18];
  float* out = (float*)d_out;

  char* p = (char*)d_ws;
  float*  h       = (float*)p;   p += (size_t)MT * DM * 4;
  float*  tmpf    = (float*)p;   p += (size_t)MT * DM * 4;
  ushort* hb      = (ushort*)p;  p += (size_t)MT * DM * 2;
  ushort* headsb  = (ushort*)p;  p += (size_t)MT * 1536 * 2;
  ushort* peb     = (ushort*)p;  p += (size_t)T_ * DM * 2;
  ushort* rkb     = (ushort*)p;  p += (size_t)T_ * DM * 2;
  ushort* avecb   = (ushort*)p;  p += (size_t)MT * DM * 2;
  ushort* xfb     = (ushort*)p;  p += (size_t)MT * INCH * 2;
  ushort* emb_wb  = (ushort*)p;  p += (size_t)DM * INCH * 2;
  ushort* qkv_wb  = (ushort*)p;  p += (size_t)4 * 1536 * DM * 2;
  ushort* rproj_wb= (ushort*)p;  p += (size_t)4 * DM * DM * 2;
  ushort* o_wb    = (ushort*)p;  p += (size_t)4 * DM * DM * 2;
  ushort* ff1_wb  = (ushort*)p;  p += (size_t)4 * DI * DM * 2;
  ushort* ff2_wb  = (ushort*)p;  p += (size_t)4 * DM * DI * 2;

  cvt_kernel<<<(DM * INCH / 4 + 255) / 256, 256, 0, stream>>>(emb_w, emb_wb, DM * INCH / 4);
  cvt_kernel<<<(4 * 1536 * DM / 4 + 255) / 256, 256, 0, stream>>>(qkv_w, qkv_wb, 4 * 1536 * DM / 4);
  cvt_kernel<<<(4 * DM * DM / 4 + 255) / 256, 256, 0, stream>>>(rproj, rproj_wb, 4 * DM * DM / 4);
  cvt_kernel<<<(4 * DM * DM / 4 + 255) / 256, 256, 0, stream>>>(o_w, o_wb, 4 * DM * DM / 4);
  cvt_kernel<<<(4 * DI * DM / 4 + 255) / 256, 256, 0, stream>>>(ff1w, ff1_wb, 4 * DI * DM / 4);
  cvt_kernel<<<(4 * DM * DI / 4 + 255) / 256, 256, 0, stream>>>(ff2w, ff2_wb, 4 * DM * DI / 4);
  pos_kernel<<<(T_ * DM) / 256, 256, 0, stream>>>(peb);
  xpose_kernel<<<dim3(T_ / 32, INCH / 32, B_), 256, 0, stream>>>(x, xfb);

  gemm_bf16<64, 2, false><<<dim3(DM / 128, MT / 64), 256, 0, stream>>>(
      xfb, emb_wb, emb_b, h, hb, MT, DM, INCH);

  for (int l = 0; l < 4; ++l) {
    gemm_bf16<128, 1, false><<<dim3(1536 / 128, MT / 128), 256, 0, stream>>>(
        hb, qkv_wb + (size_t)l * 1536 * DM, qkv_b + l * 1536, nullptr, headsb, MT, 1536, DM);
    gemm_bf16<64, 1, false><<<dim3(DM / 128, T_ / 64), 256, 0, stream>>>(
        peb, rproj_wb + (size_t)l * DM * DM, nullptr, nullptr, rkb, T_, DM, DM);
    attn_mfma_kernel<<<dim3(T_ / 64, B_ * NH), 256, 0, stream>>>(headsb, rkb, rwb, rrb, avecb);
    gemm_bf16<64, 0, false><<<dim3(DM / 128, MT / 64), 256, 0, stream>>>(
        avecb, o_wb + (size_t)l * DM * DM, nullptr, tmpf, nullptr, MT, DM, DM);
    ln_res_kernel<<<MT, 256, 0, stream>>>(h, hb, tmpf, ln1s + l * DM, ln1b + l * DM);
    gemm_bf16<128, 1, true><<<dim3(DI / 128, MT / 128), 256, 0, stream>>>(
        hb, ff1_wb + (size_t)l * DI * DM, ff1b + l * DI, nullptr, xfb, MT, DI, DM);
    gemm_bf16<64, 0, false><<<dim3(DM / 128, MT / 64), 256, 0, stream>>>(
        xfb, ff2_wb + (size_t)l * DM * DI, ff2b + l * DM, tmpf, nullptr, MT, DM, DI);
    ln_res_kernel<<<MT, 256, 0, stream>>>(h, hb, tmpf, ln2s + l * DM, ln2b + l * DM);
  }

  gemm_f32<<<dim3(1, MT / BM), 256, 0, stream>>>(h, clsw, clsb, tmpf, MT, NCLS, DM);
  reorder_kernel<<<(B_ * NCLS * T_) / 256, 256, 0, stream>>>(tmpf, out);
}

// Round 5
// 1071.463 us; speedup vs baseline: 10.8690x; 1.0964x over previous
//
#include <hip/hip_runtime.h>
#include <hip/hip_bf16.h>
#include <math.h>

// TransformerXL forward. bf16-MFMA GEMMs (BK=64, swizzled) + 2-barrier
// pipelined flash rel-attention (DMA-staged K/V/R, sel-folded BD gather,
// base-2 softmax). Layout: [t,b,*] flattened, m = t*B_ + b.

#define T_   2048
#define B_   2
#define DM   512
#define NH   8
#define DH   64
#define DI   2048
#define INCH 2048
#define NCLS 64
#define MT   4096   // T_*B_

typedef __attribute__((ext_vector_type(8))) short short8;
typedef __attribute__((ext_vector_type(4))) float float4v;

#define QSCALE 0.1803368801111204f   // 0.125 * log2(e)

__device__ inline ushort f2bf(float f) {
  uint u = __float_as_uint(f);
  return (ushort)((u + 0x7FFFu + ((u >> 16) & 1u)) >> 16);   // RNE
}
__device__ inline float bf2f(ushort h) { return __uint_as_float(((uint)h) << 16); }
__device__ inline uint pkbf(float a, float b) {
  __hip_bfloat162 h = __float22bfloat162_rn(float2{a, b});
  return *(uint*)&h;
}
__device__ inline void gload16(const void* g, void* lds) {
  __builtin_amdgcn_global_load_lds(
      (const __attribute__((address_space(1))) void*)g,
      (__attribute__((address_space(3))) void*)lds, 16, 0, 0);
}

// ---------------------------------------------------------------- pos emb (bf16 out)
__global__ __launch_bounds__(256) void pos_kernel(ushort* __restrict__ pe) {
  int idx = blockIdx.x * 256 + threadIdx.x;
  if (idx >= T_ * DM) return;
  int t = idx >> 9;
  int i = idx & 511;
  int j = (i < 256) ? i : (i - 256);
  double invf = exp(-(double)(2 * j) * (9.210340371976184 / 512.0));
  double a = (double)(T_ - 1 - t) * invf;
  pe[idx] = f2bf((i < 256) ? (float)sin(a) : (float)cos(a));
}

// ---------------------------------------------------------------- fused fp32->bf16 (6 segments)
__global__ __launch_bounds__(256) void cvt6_kernel(
    const float* s0, ushort* d0, int n0,
    const float* s1, ushort* d1, int n1,
    const float* s2, ushort* d2, int n2,
    const float* s3, ushort* d3, int n3,
    const float* s4, ushort* d4, int n4,
    const float* s5, ushort* d5, int n5)
{
  const float* s; ushort* d; int n;
  switch (blockIdx.y) {
    case 0: s = s0; d = d0; n = n0; break;
    case 1: s = s1; d = d1; n = n1; break;
    case 2: s = s2; d = d2; n = n2; break;
    case 3: s = s3; d = d3; n = n3; break;
    case 4: s = s4; d = d4; n = n4; break;
    default: s = s5; d = d5; n = n5; break;
  }
  int i = blockIdx.x * 256 + threadIdx.x;
  if (i >= n) return;
  float4 v = ((const float4*)s)[i];
  ushort4 w = { f2bf(v.x), f2bf(v.y), f2bf(v.z), f2bf(v.w) };
  ((ushort4*)d)[i] = w;
}

// ---------------------------------------------------------------- x[B,C,T] -> xb[(t*2+b), C] bf16
__global__ __launch_bounds__(256) void xpose_kernel(const float* __restrict__ x,
                                                    ushort* __restrict__ xb) {
  __shared__ float s[32][33];
  int t0 = blockIdx.x * 32, k0 = blockIdx.y * 32, b = blockIdx.z;
  int tx = threadIdx.x & 31, ty = threadIdx.x >> 5;
#pragma unroll
  for (int l = 0; l < 4; ++l) {
    int k = k0 + ty + l * 8;
    s[ty + l * 8][tx] = x[((size_t)b * INCH + k) * T_ + t0 + tx];
  }
  __syncthreads();
#pragma unroll
  for (int l = 0; l < 4; ++l) {
    int t = t0 + ty + l * 8;
    xb[((size_t)(t * 2 + b)) * INCH + k0 + tx] = f2bf(s[tx][ty + l * 8]);
  }
}

// ---------------------------------------------------------------- V transpose per layer
// heads V section (t,b,n,d) -> vtg[((b*8+n)*64+d)][t]
__global__ __launch_bounds__(256) void vtrans_kernel(const ushort* __restrict__ heads,
                                                     ushort* __restrict__ vtg) {
  __shared__ ushort s[64][72];
  const int tid = threadIdx.x;
  int t0 = blockIdx.x * 64;
  int b = blockIdx.y & 1, n = blockIdx.y >> 1;
  for (int e = tid; e < 512; e += 256) {
    int r = e >> 3, c = e & 7;
    *(uint4*)&s[r][c * 8] =
        *(const uint4*)&heads[(size_t)((t0 + r) * 2 + b) * 1536 + 1024 + n * 64 + c * 8];
  }
  __syncthreads();
  for (int e = tid; e < 512; e += 256) {
    int d = e >> 3, c = e & 7;
    ushort tmp[8];
#pragma unroll
    for (int j = 0; j < 8; ++j) tmp[j] = s[c * 8 + j][d];
    *(uint4*)&vtg[((size_t)((b * 8 + n) * 64 + d)) * (size_t)T_ + t0 + c * 8] = *(uint4*)tmp;
  }
}

// ---------------------------------------------------------------- bf16 MFMA GEMM (BK=64)
// C[m,n] = act( sum_k A[m,k]*W[n,k] + bias[n] ). A[M,K], W[N,K] bf16 row-major.
// TM in {32,64,128}. OUTMODE: 0 fp32, 1 bf16, 2 both. K multiple of 64.
template<int TM, int OUTMODE, bool RELU>
__global__ __launch_bounds__(256) void gemm_bf16(
    const ushort* __restrict__ A, const ushort* __restrict__ W,
    const float* __restrict__ bias, float* __restrict__ Cf, ushort* __restrict__ Cb,
    int M, int N, int K)
{
  __shared__ __attribute__((aligned(16))) ushort As[TM * 64];
  __shared__ __attribute__((aligned(16))) ushort Bs[128 * 64];
  const int NI = TM / 32;
  const int tid  = threadIdx.x;
  const int wave = tid >> 6, lane = tid & 63;
  const int quad = lane >> 4, lidx = lane & 15;
  const int m0 = blockIdx.y * TM, n0 = blockIdx.x * 128;
  const int r8 = lane >> 3;                       // staging row within 8-row chunk
  const int cs = ((lane & 7) ^ (r8 & 7)) * 8;     // swizzled chunk (ushort offset)

  float4v acc[NI * 4];
#pragma unroll
  for (int i = 0; i < NI * 4; ++i) acc[i] = (float4v){0.f, 0.f, 0.f, 0.f};

  const int wm = (wave >> 1) * (TM / 2), wn = (wave & 1) * 64;

  for (int k0 = 0; k0 < K; k0 += 64) {
    __syncthreads();
#pragma unroll
    for (int g = 0; g < TM / 32; ++g) {
      int r0 = wave * 8 + g * 32;
      gload16(A + (size_t)(m0 + r0 + r8) * K + k0 + cs, &As[r0 * 64]);
    }
#pragma unroll
    for (int g = 0; g < 4; ++g) {
      int r0 = wave * 8 + g * 32;
      gload16(W + (size_t)(n0 + r0 + r8) * K + k0 + cs, &Bs[r0 * 64]);
    }
    __syncthreads();

#pragma unroll
    for (int kb = 0; kb < 2; ++kb) {
      short8 af[NI], bf4[4];
      const int ch = (((kb * 4 + quad) ^ (lidx & 7)) * 8);
#pragma unroll
      for (int i = 0; i < NI; ++i)
        af[i] = *(const short8*)&As[(wm + i * 16 + lidx) * 64 + ch];
#pragma unroll
      for (int j = 0; j < 4; ++j)
        bf4[j] = *(const short8*)&Bs[(wn + j * 16 + lidx) * 64 + ch];
#pragma unroll
      for (int i = 0; i < NI; ++i)
#pragma unroll
        for (int j = 0; j < 4; ++j)
          acc[i * 4 + j] = __builtin_amdgcn_mfma_f32_16x16x32_bf16(af[i], bf4[j], acc[i * 4 + j], 0, 0, 0);
    }
  }

  float bj[4];
#pragma unroll
  for (int j = 0; j < 4; ++j) bj[j] = bias ? bias[n0 + wn + j * 16 + lidx] : 0.f;
#pragma unroll
  for (int i = 0; i < NI; ++i) {
    int rbase = m0 + wm + i * 16 + quad * 4;
#pragma unroll
    for (int j = 0; j < 4; ++j) {
      int col = n0 + wn + j * 16 + lidx;
#pragma unroll
      for (int reg = 0; reg < 4; ++reg) {
        float v = acc[i * 4 + j][reg] + bj[j];
        if (RELU) v = fmaxf(v, 0.f);
        size_t off = (size_t)(rbase + reg) * N + col;
        if (OUTMODE != 1) Cf[off] = v;
        if (OUTMODE != 0) Cb[off] = f2bf(v);
      }
    }
  }
}

// ---------------------------------------------------------------- fp32 GEMM (cls only)
#define BM 128
#define BN 128
#define BK 16
#define LDT 132

__global__ __launch_bounds__(256) void gemm_f32(
    const float* __restrict__ A, const float* __restrict__ W,
    const float* __restrict__ bias, float* __restrict__ C,
    int M, int N, int K)
{
  __shared__ float Asm[BK][LDT];
  __shared__ float Wsm[BK][LDT];
  const int tid = threadIdx.x;
  const int m0 = blockIdx.y * BM;
  const int n0 = blockIdx.x * BN;
  const int row = tid >> 1;
  const int kh  = (tid & 1) * 8;
  const int ty  = tid >> 4;
  const int tx  = tid & 15;

  float acc[8][8];
#pragma unroll
  for (int i = 0; i < 8; ++i)
#pragma unroll
    for (int j = 0; j < 8; ++j) acc[i][j] = 0.f;

  for (int kt = 0; kt < K; kt += BK) {
    float a_reg[8], w_reg[8];
    {
      const float* ap = A + (size_t)(m0 + row) * K + (kt + kh);
      float4 v0 = *(const float4*)ap;
      float4 v1 = *(const float4*)(ap + 4);
      a_reg[0] = v0.x; a_reg[1] = v0.y; a_reg[2] = v0.z; a_reg[3] = v0.w;
      a_reg[4] = v1.x; a_reg[5] = v1.y; a_reg[6] = v1.z; a_reg[7] = v1.w;
    }
    {
      int nn = n0 + row;
      if (nn < N) {
        const float* wp = W + (size_t)nn * K + (kt + kh);
        float4 v0 = *(const float4*)wp;
        float4 v1 = *(const float4*)(wp + 4);
        w_reg[0] = v0.x; w_reg[1] = v0.y; w_reg[2] = v0.z; w_reg[3] = v0.w;
        w_reg[4] = v1.x; w_reg[5] = v1.y; w_reg[6] = v1.z; w_reg[7] = v1.w;
      } else {
#pragma unroll
        for (int q = 0; q < 8; ++q) w_reg[q] = 0.f;
      }
    }
    __syncthreads();
#pragma unroll
    for (int q = 0; q < 8; ++q) { Asm[kh + q][row] = a_reg[q]; Wsm[kh + q][row] = w_reg[q]; }
    __syncthreads();
#pragma unroll
    for (int k = 0; k < BK; ++k) {
      float4 a0 = *(const float4*)&Asm[k][ty * 4];
      float4 a1 = *(const float4*)&Asm[k][ty * 4 + 64];
      float4 b0 = *(const float4*)&Wsm[k][tx * 4];
      float4 b1 = *(const float4*)&Wsm[k][tx * 4 + 64];
      float av[8] = {a0.x, a0.y, a0.z, a0.w, a1.x, a1.y, a1.z, a1.w};
      float bv[8] = {b0.x, b0.y, b0.z, b0.w, b1.x, b1.y, b1.z, b1.w};
#pragma unroll
      for (int i = 0; i < 8; ++i)
#pragma unroll
        for (int j = 0; j < 8; ++j) acc[i][j] += av[i] * bv[j];
    }
  }

#pragma unroll
  for (int ih = 0; ih < 2; ++ih)
#pragma unroll
    for (int i = 0; i < 4; ++i) {
      int m = m0 + ty * 4 + ih * 64 + i;
#pragma unroll
      for (int jh = 0; jh < 2; ++jh) {
        int nn = n0 + tx * 4 + jh * 64;
        if (nn < N) {
          float4 v;
          v.x = acc[ih * 4 + i][jh * 4 + 0] + bias[nn + 0];
          v.y = acc[ih * 4 + i][jh * 4 + 1] + bias[nn + 1];
          v.z = acc[ih * 4 + i][jh * 4 + 2] + bias[nn + 2];
          v.w = acc[ih * 4 + i][jh * 4 + 3] + bias[nn + 3];
          *(float4*)&C[(size_t)m * N + nn] = v;
        }
      }
    }
}

// ---------------------------------------------------------------- MFMA flash rel-attn
// Block: 64 query rows of one (b,n); wave owns a 16-row strip. 64-key tiles.
// rel_shift (no mask) wraps: BD[i,j] = Qr[i+sel].Rext[qh], qh = j+T-1-i,
// sel = qh>T; Rext[qh<T]=rk[qh], Rext[T]=0, Rext[qh>T]=rk[qh-T-1].
// G stored sel-folded: Gbt[w][grow-sel(w)] so gather addr is loop-invariant.
// 2 barriers/iter; K/Re prefetch overlaps softmax+PV; Vt prefetch overlaps AC/G.
#define GT 66

__global__ __launch_bounds__(256) void attn_mfma_kernel(
    const ushort* __restrict__ heads, const ushort* __restrict__ rk,
    const ushort* __restrict__ vtg,
    const float* __restrict__ rwb, const float* __restrict__ rrb,
    ushort* __restrict__ avec)
{
  __shared__ __attribute__((aligned(16))) ushort Ks[64 * 64];    // swizzled [key][d]
  __shared__ __attribute__((aligned(16))) ushort Vt[64 * 64];    // swizzled [d][key]
  __shared__ __attribute__((aligned(16))) ushort Re[128 * 64];   // swizzled [w][d]
  __shared__ __attribute__((aligned(16))) ushort Gbt[128 * GT];  // [w][gcol]
  __shared__ __attribute__((aligned(16))) ushort Pb[64 * 64];    // swizzled [row][key]

  const int tid  = threadIdx.x;
  const int i0   = blockIdx.x * 64;
  const int b    = blockIdx.y & 1;
  const int n    = blockIdx.y >> 1;
  const int wv   = tid >> 6;
  const int lane = tid & 63;
  const int quad = lane >> 4;
  const int lidx = lane & 15;
  const int r8   = lane >> 3;
  const int cs8  = ((lane & 7) ^ (r8 & 7)) * 8;
  const int bn64 = (b * 8 + n) * 64;

  const int swoff0 = lidx * 128 + ((quad ^ (lidx & 7)) * 16);
  const int swoff1 = lidx * 128 + (((4 + quad) ^ (lidx & 7)) * 16);

  // ---- Q fragments (scaled by QSCALE) in registers
  short8 qw0, qw1, qr0, qr1, q40, q41;
  {
    auto qfrag = [&](int row, int kb, const float* bias) -> short8 {
      short8 q;
      if (row < T_) q = *(const short8*)&heads[(size_t)(row * 2 + b) * 1536 + n * 64 + kb * 32 + quad * 8];
      else { for (int t = 0; t < 8; ++t) ((ushort*)&q)[t] = 0; }
      short8 o;
#pragma unroll
      for (int t = 0; t < 8; ++t) {
        float f = (bf2f((ushort)((ushort*)&q)[t]) + bias[n * 64 + kb * 32 + quad * 8 + t]) * QSCALE;
        ((ushort*)&o)[t] = f2bf(f);
      }
      return o;
    };
    int rown = i0 + 16 * wv + lidx;
    qw0 = qfrag(rown, 0, rwb); qw1 = qfrag(rown, 1, rwb);
    qr0 = qfrag(rown, 0, rrb); qr1 = qfrag(rown, 1, rrb);
    int row4 = i0 + 64 + lidx;
    q40 = qfrag(row4, 0, rrb); q41 = qfrag(row4, 1, rrb);
  }

  const int rbase = 16 * wv + quad * 4;

  // loop-invariant gather / P-store addresses (ushort indices)
  int addrG[4][4], addrP[4][4];
#pragma unroll
  for (int ct = 0; ct < 4; ++ct)
#pragma unroll
    for (int reg = 0; reg < 4; ++reg) {
      int rloc = rbase + reg;
      int w = ct * 16 + lidx + 63 - rloc;
      addrG[ct][reg] = w * GT + rloc;
      int col = ct * 16 + lidx;
      int scc = (col >> 3) ^ (rloc & 7);
      addrP[ct][reg] = rloc * 64 + scc * 8 + (col & 7);
    }

  float4v oacc[4];
#pragma unroll
  for (int d = 0; d < 4; ++d) oacc[d] = (float4v){0.f, 0.f, 0.f, 0.f};
  float mi[4] = {-INFINITY, -INFINITY, -INFINITY, -INFINITY};
  float li[4] = {0.f, 0.f, 0.f, 0.f};
  float al[4];

  auto stageKRe = [&](int jt) {
    int j0 = jt * 64, qmin = j0 + 1984 - i0;
#pragma unroll
    for (int half = 0; half < 2; ++half) {
      int r0 = 8 * wv + 32 * half;
      gload16(heads + (size_t)((j0 + r0 + r8) * 2 + b) * 1536 + 512 + n * 64 + cs8, &Ks[r0 * 64]);
    }
#pragma unroll
    for (int q4 = 0; q4 < 4; ++q4) {
      int r0 = 8 * wv + 32 * q4;
      int qh = qmin + r0 + r8;
      int p  = (qh > T_) ? (qh - T_ - 1) : ((qh == T_) ? 0 : qh);
      gload16(rk + (size_t)p * 2048 + n * 64 + cs8, &Re[r0 * 64]);
    }
  };
  auto stageV = [&](int jt) {
    int j0 = jt * 64;
#pragma unroll
    for (int half = 0; half < 2; ++half) {
      int r0 = 8 * wv + 32 * half;
      gload16(vtg + (size_t)(bn64 + r0 + r8) * (size_t)T_ + j0 + cs8, &Vt[r0 * 64]);
    }
  };
  auto fixup = [&](int jt) {   // zero Rext[T] row (after DMA drained)
    int qmin = jt * 64 + 1984 - i0;
    int Tidx = T_ - qmin;
    if (Tidx >= 0 && Tidx < 128) {
      if (tid < 32) ((uint*)Re)[Tidx * 32 + tid] = 0u;
      __syncthreads();
    }
  };

  stageKRe(0);
  stageV(0);
  __syncthreads();
  fixup(0);

  for (int jt = 0; jt < 32; ++jt) {
    const int qmin = jt * 64 + 1984 - i0;

    // ---- AC: S strip in registers
    float4v sv[4];
#pragma unroll
    for (int ct = 0; ct < 4; ++ct) {
      float4v c = {0.f, 0.f, 0.f, 0.f};
      short8 b0 = *(const short8*)((const char*)Ks + ct * 2048 + swoff0);
      short8 b1 = *(const short8*)((const char*)Ks + ct * 2048 + swoff1);
      c = __builtin_amdgcn_mfma_f32_16x16x32_bf16(qw0, b0, c, 0, 0, 0);
      c = __builtin_amdgcn_mfma_f32_16x16x32_bf16(qw1, b1, c, 0, 0, 0);
      sv[ct] = c;
    }
    // ---- G tiles, sel-folded stores
    {
      int ws = 48 - 16 * wv;
#pragma unroll
      for (int tt = 0; tt < 5; ++tt) {
        int w0 = ws + 16 * tt;
        float4v g = {0.f, 0.f, 0.f, 0.f};
        short8 b0 = *(const short8*)((const char*)Re + w0 * 128 + swoff0);
        short8 b1 = *(const short8*)((const char*)Re + w0 * 128 + swoff1);
        g = __builtin_amdgcn_mfma_f32_16x16x32_bf16(qr0, b0, g, 0, 0, 0);
        g = __builtin_amdgcn_mfma_f32_16x16x32_bf16(qr1, b1, g, 0, 0, 0);
        int w = w0 + lidx;
        int sel = (qmin + w > T_) ? 1 : 0;
        int gc = 16 * wv + quad * 4 - sel;
        uint p01 = pkbf(g[0], g[1]), p23 = pkbf(g[2], g[3]);
        ushort* gp = &Gbt[w * GT + gc];
        if (gc >= 0) gp[0] = (ushort)p01;
        gp[1] = (ushort)(p01 >> 16);
        gp[2] = (ushort)p23;
        gp[3] = (ushort)(p23 >> 16);
      }
      // grow=64 strip (only needed where sel==1)
      int w0 = 16 * wv;
      if (qmin + w0 + 15 > T_) {
        float4v g = {0.f, 0.f, 0.f, 0.f};
        short8 b0 = *(const short8*)((const char*)Re + w0 * 128 + swoff0);
        short8 b1 = *(const short8*)((const char*)Re + w0 * 128 + swoff1);
        g = __builtin_amdgcn_mfma_f32_16x16x32_bf16(q40, b0, g, 0, 0, 0);
        g = __builtin_amdgcn_mfma_f32_16x16x32_bf16(q41, b1, g, 0, 0, 0);
        int w = w0 + lidx;
        if (quad == 0 && (qmin + w > T_)) Gbt[w * GT + 63] = f2bf(g[0]);
      }
    }
    __syncthreads();                 // Gbt ready; Ks/Re consumed

    if (jt < 31) stageKRe(jt + 1);   // DMA overlaps softmax+PV

    // ---- gather BD + base-2 online softmax (per-wave rows)
    {
      float x[4][4];
#pragma unroll
      for (int ct = 0; ct < 4; ++ct)
#pragma unroll
        for (int reg = 0; reg < 4; ++reg)
          x[ct][reg] = sv[ct][reg] + bf2f(Gbt[addrG[ct][reg]]);
#pragma unroll
      for (int reg = 0; reg < 4; ++reg) {
        float m = fmaxf(fmaxf(x[0][reg], x[1][reg]), fmaxf(x[2][reg], x[3][reg]));
        m = fmaxf(m, __shfl_xor(m, 1));
        m = fmaxf(m, __shfl_xor(m, 2));
        m = fmaxf(m, __shfl_xor(m, 4));
        m = fmaxf(m, __shfl_xor(m, 8));
        float mnew = fmaxf(mi[reg], m);
        al[reg] = exp2f(mi[reg] - mnew);
        float p0 = exp2f(x[0][reg] - mnew);
        float p1 = exp2f(x[1][reg] - mnew);
        float p2 = exp2f(x[2][reg] - mnew);
        float p3 = exp2f(x[3][reg] - mnew);
        float ls = p0 + p1 + p2 + p3;
        uint a01 = pkbf(p0, p1), a23 = pkbf(p2, p3);
        Pb[addrP[0][reg]] = (ushort)a01;
        Pb[addrP[1][reg]] = (ushort)(a01 >> 16);
        Pb[addrP[2][reg]] = (ushort)a23;
        Pb[addrP[3][reg]] = (ushort)(a23 >> 16);
        ls += __shfl_xor(ls, 1);
        ls += __shfl_xor(ls, 2);
        ls += __shfl_xor(ls, 4);
        ls += __shfl_xor(ls, 8);
        li[reg] = li[reg] * al[reg] + ls;
        mi[reg] = mnew;
      }
    }

    // ---- PV: O strip += P . V  (reads only own wave's Pb strip)
    {
      short8 pa0 = *(const short8*)((const char*)Pb + 16 * wv * 128 + swoff0);
      short8 pa1 = *(const short8*)((const char*)Pb + 16 * wv * 128 + swoff1);
#pragma unroll
      for (int dt = 0; dt < 4; ++dt) {
        float4v c;
#pragma unroll
        for (int reg = 0; reg < 4; ++reg) c[reg] = oacc[dt][reg] * al[reg];
        short8 vb0 = *(const short8*)((const char*)Vt + dt * 2048 + swoff0);
        short8 vb1 = *(const short8*)((const char*)Vt + dt * 2048 + swoff1);
        c = __builtin_amdgcn_mfma_f32_16x16x32_bf16(pa0, vb0, c, 0, 0, 0);
        c = __builtin_amdgcn_mfma_f32_16x16x32_bf16(pa1, vb1, c, 0, 0, 0);
        oacc[dt] = c;
      }
    }
    __syncthreads();                 // Vt consumed; drains K/Re DMA for jt+1

    if (jt < 31) {
      stageV(jt + 1);                // DMA overlaps next AC/G
      fixup(jt + 1);
    }
  }

  // ---- epilogue
#pragma unroll
  for (int dt = 0; dt < 4; ++dt) {
#pragma unroll
    for (int reg = 0; reg < 4; ++reg) {
      int i = i0 + rbase + reg;
      float val = oacc[dt][reg] / li[reg];
      avec[(size_t)(i * 2 + b) * DM + n * 64 + dt * 16 + lidx] = f2bf(val);
    }
  }
}

// ---------------------------------------------------------------- LN(residual), dual out
__global__ __launch_bounds__(256) void ln_res_kernel(
    float* __restrict__ h, ushort* __restrict__ hb, const float* __restrict__ delta,
    const float* __restrict__ s, const float* __restrict__ bb)
{
  const int m = blockIdx.x;
  const int tid = threadIdx.x;
  float* hp = h + (size_t)m * DM;
  ushort* hbp = hb + (size_t)m * DM;
  const float* dp = delta + (size_t)m * DM;
  float x0 = hp[tid] + dp[tid];
  float x1 = hp[tid + 256] + dp[tid + 256];
  float sum = x0 + x1, sq = x0 * x0 + x1 * x1;
#pragma unroll
  for (int o = 32; o > 0; o >>= 1) { sum += __shfl_down(sum, o); sq += __shfl_down(sq, o); }
  __shared__ float part[8];
  int wv = tid >> 6;
  if ((tid & 63) == 0) { part[wv * 2] = sum; part[wv * 2 + 1] = sq; }
  __syncthreads();
  float ts = part[0] + part[2] + part[4] + part[6];
  float tq = part[1] + part[3] + part[5] + part[7];
  float mu = ts * (1.f / DM);
  float var = tq * (1.f / DM) - mu * mu;
  float rs = rsqrtf(var + 1e-5f);
  float y0 = (x0 - mu) * rs * s[tid]       + bb[tid];
  float y1 = (x1 - mu) * rs * s[tid + 256] + bb[tid + 256];
  hp[tid] = y0;       hbp[tid] = f2bf(y0);
  hp[tid + 256] = y1; hbp[tid + 256] = f2bf(y1);
}

// ---------------------------------------------------------------- classifier reorder
__global__ __launch_bounds__(256) void reorder_kernel(const float* __restrict__ ct,
                                                      float* __restrict__ out) {
  int idx = blockIdx.x * 256 + threadIdx.x;
  if (idx >= B_ * NCLS * T_) return;
  int t  = idx & (T_ - 1);
  int nc = (idx >> 11) & 63;
  int bb = idx >> 17;
  out[idx] = ct[(size_t)(t * B_ + bb) * NCLS + nc];
}

// ---------------------------------------------------------------- launch
extern "C" void kernel_launch(void* const* d_in, const int* in_sizes, int n_in,
                              void* d_out, int out_size, void* d_ws, size_t ws_size,
                              hipStream_t stream)
{
  const float* x     = (const float*)d_in[0];
  const float* emb_w = (const float*)d_in[1];
  const float* emb_b = (const float*)d_in[2];
  const float* rwb   = (const float*)d_in[3];
  const float* rrb   = (const float*)d_in[4];
  const float* qkv_w = (const float*)d_in[5];
  const float* qkv_b = (const float*)d_in[6];
  const float* rproj = (const float*)d_in[7];
  const float* o_w   = (const float*)d_in[8];
  const float* ln1s  = (const float*)d_in[9];
  const float* ln1b  = (const float*)d_in[10];
  const float* ff1w  = (const float*)d_in[11];
  const float* ff1b  = (const float*)d_in[12];
  const float* ff2w  = (const float*)d_in[13];
  const float* ff2b  = (const float*)d_in[14];
  const float* ln2s  = (const float*)d_in[15];
  const float* ln2b  = (const float*)d_in[16];
  const float* clsw  = (const float*)d_in[17];
  const float* clsb  = (const float*)d_in[18];
  float* out = (float*)d_out;

  char* p = (char*)d_ws;
  float*  h       = (float*)p;   p += (size_t)MT * DM * 4;        // 8 MB
  float*  tmpf    = (float*)p;   p += (size_t)MT * DM * 4;        // 8 MB
  ushort* hb      = (ushort*)p;  p += (size_t)MT * DM * 2;        // 4 MB
  ushort* headsb  = (ushort*)p;  p += (size_t)MT * 1536 * 2;      // 12 MB
  ushort* peb     = (ushort*)p;  p += (size_t)T_ * DM * 2;        // 2 MB
  ushort* rk_all  = (ushort*)p;  p += (size_t)T_ * 2048 * 2;      // 8 MB (4 layers)
  ushort* avecb   = (ushort*)p;  p += (size_t)MT * DM * 2;        // 4 MB
  ushort* xfb     = (ushort*)p;  p += (size_t)MT * INCH * 2;      // 16 MB (xb / ff1-out / vtg)
  ushort* emb_wb  = (ushort*)p;  p += (size_t)DM * INCH * 2;      // 2 MB
  ushort* qkv_wb  = (ushort*)p;  p += (size_t)4 * 1536 * DM * 2;  // 6 MB
  ushort* rproj_wb= (ushort*)p;  p += (size_t)4 * DM * DM * 2;    // 2 MB
  ushort* o_wb    = (ushort*)p;  p += (size_t)4 * DM * DM * 2;    // 2 MB
  ushort* ff1_wb  = (ushort*)p;  p += (size_t)4 * DI * DM * 2;    // 8 MB
  ushort* ff2_wb  = (ushort*)p;  p += (size_t)4 * DM * DI * 2;    // 8 MB
  ushort* vtg     = xfb;         // 2 MB region of xfb; live only vtrans->attn

  cvt6_kernel<<<dim3(4096, 6), 256, 0, stream>>>(
      emb_w, emb_wb, DM * INCH / 4,
      qkv_w, qkv_wb, 4 * 1536 * DM / 4,
      rproj, rproj_wb, 4 * DM * DM / 4,
      o_w,   o_wb,   4 * DM * DM / 4,
      ff1w,  ff1_wb, 4 * DI * DM / 4,
      ff2w,  ff2_wb, 4 * DM * DI / 4);
  pos_kernel<<<(T_ * DM) / 256, 256, 0, stream>>>(peb);
  xpose_kernel<<<dim3(T_ / 32, INCH / 32, B_), 256, 0, stream>>>(x, xfb);

  // embed: h fp32 + hb bf16
  gemm_bf16<64, 2, false><<<dim3(DM / 128, MT / 64), 256, 0, stream>>>(
      xfb, emb_wb, emb_b, h, hb, MT, DM, INCH);
  // batched r_proj for all 4 layers: rk_all[t][l*512+e]
  gemm_bf16<128, 1, false><<<dim3(2048 / 128, T_ / 128), 256, 0, stream>>>(
      peb, rproj_wb, nullptr, nullptr, rk_all, T_, 2048, DM);

  for (int l = 0; l < 4; ++l) {
    gemm_bf16<128, 1, false><<<dim3(1536 / 128, MT / 128), 256, 0, stream>>>(
        hb, qkv_wb + (size_t)l * 1536 * DM, qkv_b + l * 1536, nullptr, headsb, MT, 1536, DM);
    vtrans_kernel<<<dim3(T_ / 64, B_ * NH), 256, 0, stream>>>(headsb, vtg);
    attn_mfma_kernel<<<dim3(T_ / 64, B_ * NH), 256, 0, stream>>>(
        headsb, rk_all + (size_t)l * 512, vtg, rwb, rrb, avecb);
    gemm_bf16<32, 0, false><<<dim3(DM / 128, MT / 32), 256, 0, stream>>>(
        avecb, o_wb + (size_t)l * DM * DM, nullptr, tmpf, nullptr, MT, DM, DM);
    ln_res_kernel<<<MT, 256, 0, stream>>>(h, hb, tmpf, ln1s + l * DM, ln1b + l * DM);
    gemm_bf16<128, 1, true><<<dim3(DI / 128, MT / 128), 256, 0, stream>>>(
        hb, ff1_wb + (size_t)l * DI * DM, ff1b + l * DI, nullptr, xfb, MT, DI, DM);
    gemm_bf16<32, 0, false><<<dim3(DM / 128, MT / 32), 256, 0, stream>>>(
        xfb, ff2_wb + (size_t)l * DM * DI, ff2b + l * DM, tmpf, nullptr, MT, DM, DI);
    ln_res_kernel<<<MT, 256, 0, stream>>>(h, hb, tmpf, ln2s + l * DM, ln2b + l * DM);
  }

  gemm_f32<<<dim3(1, MT / BM), 256, 0, stream>>>(h, clsw, clsb, tmpf, MT, NCLS, DM);
  reorder_kernel<<<(B_ * NCLS * T_) / 256, 256, 0, stream>>>(tmpf, out);
}

// Round 6
// 969.244 us; speedup vs baseline: 12.0152x; 1.1055x over previous
//
#include <hip/hip_runtime.h>
#include <hip/hip_bf16.h>
#include <math.h>

// TransformerXL forward. bf16-MFMA GEMMs (BK=64, swizzled) + column-strip
// flash rel-attention: Q in registers, B-frag reuse (16 b128/wave-iter),
// no-max base-2 softmax (bounded scores), li via ones-MFMA.
// Layout: [t,b,*] flattened, m = t*B_ + b.

#define T_   2048
#define B_   2
#define DM   512
#define NH   8
#define DH   64
#define DI   2048
#define INCH 2048
#define NCLS 64
#define MT   4096   // T_*B_

typedef __attribute__((ext_vector_type(8))) short short8;
typedef __attribute__((ext_vector_type(4))) float float4v;

#define QSCALE 0.1803368801111204f   // 0.125 * log2(e)

__device__ inline ushort f2bf(float f) {
  uint u = __float_as_uint(f);
  return (ushort)((u + 0x7FFFu + ((u >> 16) & 1u)) >> 16);   // RNE
}
__device__ inline float bf2f(ushort h) { return __uint_as_float(((uint)h) << 16); }
__device__ inline uint pkbf(float a, float b) {
  __hip_bfloat162 h = __float22bfloat162_rn(float2{a, b});
  return *(uint*)&h;
}
__device__ inline void gload16(const void* g, void* lds) {
  __builtin_amdgcn_global_load_lds(
      (const __attribute__((address_space(1))) void*)g,
      (__attribute__((address_space(3))) void*)lds, 16, 0, 0);
}

// ---------------------------------------------------------------- pos emb (bf16 out)
__global__ __launch_bounds__(256) void pos_kernel(ushort* __restrict__ pe) {
  int idx = blockIdx.x * 256 + threadIdx.x;
  if (idx >= T_ * DM) return;
  int t = idx >> 9;
  int i = idx & 511;
  int j = (i < 256) ? i : (i - 256);
  double invf = exp(-(double)(2 * j) * (9.210340371976184 / 512.0));
  double a = (double)(T_ - 1 - t) * invf;
  pe[idx] = f2bf((i < 256) ? (float)sin(a) : (float)cos(a));
}

// ---------------------------------------------------------------- fused fp32->bf16 (6 segments)
__global__ __launch_bounds__(256) void cvt6_kernel(
    const float* s0, ushort* d0, int n0,
    const float* s1, ushort* d1, int n1,
    const float* s2, ushort* d2, int n2,
    const float* s3, ushort* d3, int n3,
    const float* s4, ushort* d4, int n4,
    const float* s5, ushort* d5, int n5)
{
  const float* s; ushort* d; int n;
  switch (blockIdx.y) {
    case 0: s = s0; d = d0; n = n0; break;
    case 1: s = s1; d = d1; n = n1; break;
    case 2: s = s2; d = d2; n = n2; break;
    case 3: s = s3; d = d3; n = n3; break;
    case 4: s = s4; d = d4; n = n4; break;
    default: s = s5; d = d5; n = n5; break;
  }
  int i = blockIdx.x * 256 + threadIdx.x;
  if (i >= n) return;
  float4 v = ((const float4*)s)[i];
  ushort4 w = { f2bf(v.x), f2bf(v.y), f2bf(v.z), f2bf(v.w) };
  ((ushort4*)d)[i] = w;
}

// ---------------------------------------------------------------- x[B,C,T] -> xb[(t*2+b), C] bf16
__global__ __launch_bounds__(256) void xpose_kernel(const float* __restrict__ x,
                                                    ushort* __restrict__ xb) {
  __shared__ float s[32][33];
  int t0 = blockIdx.x * 32, k0 = blockIdx.y * 32, b = blockIdx.z;
  int tx = threadIdx.x & 31, ty = threadIdx.x >> 5;
#pragma unroll
  for (int l = 0; l < 4; ++l) {
    int k = k0 + ty + l * 8;
    s[ty + l * 8][tx] = x[((size_t)b * INCH + k) * T_ + t0 + tx];
  }
  __syncthreads();
#pragma unroll
  for (int l = 0; l < 4; ++l) {
    int t = t0 + ty + l * 8;
    xb[((size_t)(t * 2 + b)) * INCH + k0 + tx] = f2bf(s[tx][ty + l * 8]);
  }
}

// ---------------------------------------------------------------- V transpose per layer
// heads V section (t,b,n,d) -> vtg[((b*8+n)*64+d)][t]
__global__ __launch_bounds__(256) void vtrans_kernel(const ushort* __restrict__ heads,
                                                     ushort* __restrict__ vtg) {
  __shared__ ushort s[64][72];
  const int tid = threadIdx.x;
  int t0 = blockIdx.x * 64;
  int b = blockIdx.y & 1, n = blockIdx.y >> 1;
  for (int e = tid; e < 512; e += 256) {
    int r = e >> 3, c = e & 7;
    *(uint4*)&s[r][c * 8] =
        *(const uint4*)&heads[(size_t)((t0 + r) * 2 + b) * 1536 + 1024 + n * 64 + c * 8];
  }
  __syncthreads();
  for (int e = tid; e < 512; e += 256) {
    int d = e >> 3, c = e & 7;
    ushort tmp[8];
#pragma unroll
    for (int j = 0; j < 8; ++j) tmp[j] = s[c * 8 + j][d];
    *(uint4*)&vtg[((size_t)((b * 8 + n) * 64 + d)) * (size_t)T_ + t0 + c * 8] = *(uint4*)tmp;
  }
}

// ---------------------------------------------------------------- bf16 MFMA GEMM (BK=64)
template<int TM, int OUTMODE, bool RELU>
__global__ __launch_bounds__(256) void gemm_bf16(
    const ushort* __restrict__ A, const ushort* __restrict__ W,
    const float* __restrict__ bias, float* __restrict__ Cf, ushort* __restrict__ Cb,
    int M, int N, int K)
{
  __shared__ __attribute__((aligned(16))) ushort As[TM * 64];
  __shared__ __attribute__((aligned(16))) ushort Bs[128 * 64];
  const int NI = TM / 32;
  const int tid  = threadIdx.x;
  const int wave = tid >> 6, lane = tid & 63;
  const int quad = lane >> 4, lidx = lane & 15;
  const int m0 = blockIdx.y * TM, n0 = blockIdx.x * 128;
  const int r8 = lane >> 3;
  const int cs = ((lane & 7) ^ (r8 & 7)) * 8;

  float4v acc[NI * 4];
#pragma unroll
  for (int i = 0; i < NI * 4; ++i) acc[i] = (float4v){0.f, 0.f, 0.f, 0.f};

  const int wm = (wave >> 1) * (TM / 2), wn = (wave & 1) * 64;

  for (int k0 = 0; k0 < K; k0 += 64) {
    __syncthreads();
#pragma unroll
    for (int g = 0; g < TM / 32; ++g) {
      int r0 = wave * 8 + g * 32;
      gload16(A + (size_t)(m0 + r0 + r8) * K + k0 + cs, &As[r0 * 64]);
    }
#pragma unroll
    for (int g = 0; g < 4; ++g) {
      int r0 = wave * 8 + g * 32;
      gload16(W + (size_t)(n0 + r0 + r8) * K + k0 + cs, &Bs[r0 * 64]);
    }
    __syncthreads();

#pragma unroll
    for (int kb = 0; kb < 2; ++kb) {
      short8 af[NI], bf4[4];
      const int ch = (((kb * 4 + quad) ^ (lidx & 7)) * 8);
#pragma unroll
      for (int i = 0; i < NI; ++i)
        af[i] = *(const short8*)&As[(wm + i * 16 + lidx) * 64 + ch];
#pragma unroll
      for (int j = 0; j < 4; ++j)
        bf4[j] = *(const short8*)&Bs[(wn + j * 16 + lidx) * 64 + ch];
#pragma unroll
      for (int i = 0; i < NI; ++i)
#pragma unroll
        for (int j = 0; j < 4; ++j)
          acc[i * 4 + j] = __builtin_amdgcn_mfma_f32_16x16x32_bf16(af[i], bf4[j], acc[i * 4 + j], 0, 0, 0);
    }
  }

  float bj[4];
#pragma unroll
  for (int j = 0; j < 4; ++j) bj[j] = bias ? bias[n0 + wn + j * 16 + lidx] : 0.f;
#pragma unroll
  for (int i = 0; i < NI; ++i) {
    int rbase = m0 + wm + i * 16 + quad * 4;
#pragma unroll
    for (int j = 0; j < 4; ++j) {
      int col = n0 + wn + j * 16 + lidx;
#pragma unroll
      for (int reg = 0; reg < 4; ++reg) {
        float v = acc[i * 4 + j][reg] + bj[j];
        if (RELU) v = fmaxf(v, 0.f);
        size_t off = (size_t)(rbase + reg) * N + col;
        if (OUTMODE != 1) Cf[off] = v;
        if (OUTMODE != 0) Cb[off] = f2bf(v);
      }
    }
  }
}

// ---------------------------------------------------------------- fp32 GEMM (cls only)
#define BM 128
#define BN 128
#define BK 16
#define LDT 132

__global__ __launch_bounds__(256) void gemm_f32(
    const float* __restrict__ A, const float* __restrict__ W,
    const float* __restrict__ bias, float* __restrict__ C,
    int M, int N, int K)
{
  __shared__ float Asm[BK][LDT];
  __shared__ float Wsm[BK][LDT];
  const int tid = threadIdx.x;
  const int m0 = blockIdx.y * BM;
  const int n0 = blockIdx.x * BN;
  const int row = tid >> 1;
  const int kh  = (tid & 1) * 8;
  const int ty  = tid >> 4;
  const int tx  = tid & 15;

  float acc[8][8];
#pragma unroll
  for (int i = 0; i < 8; ++i)
#pragma unroll
    for (int j = 0; j < 8; ++j) acc[i][j] = 0.f;

  for (int kt = 0; kt < K; kt += BK) {
    float a_reg[8], w_reg[8];
    {
      const float* ap = A + (size_t)(m0 + row) * K + (kt + kh);
      float4 v0 = *(const float4*)ap;
      float4 v1 = *(const float4*)(ap + 4);
      a_reg[0] = v0.x; a_reg[1] = v0.y; a_reg[2] = v0.z; a_reg[3] = v0.w;
      a_reg[4] = v1.x; a_reg[5] = v1.y; a_reg[6] = v1.z; a_reg[7] = v1.w;
    }
    {
      int nn = n0 + row;
      if (nn < N) {
        const float* wp = W + (size_t)nn * K + (kt + kh);
        float4 v0 = *(const float4*)wp;
        float4 v1 = *(const float4*)(wp + 4);
        w_reg[0] = v0.x; w_reg[1] = v0.y; w_reg[2] = v0.z; w_reg[3] = v0.w;
        w_reg[4] = v1.x; w_reg[5] = v1.y; w_reg[6] = v1.z; w_reg[7] = v1.w;
      } else {
#pragma unroll
        for (int q = 0; q < 8; ++q) w_reg[q] = 0.f;
      }
    }
    __syncthreads();
#pragma unroll
    for (int q = 0; q < 8; ++q) { Asm[kh + q][row] = a_reg[q]; Wsm[kh + q][row] = w_reg[q]; }
    __syncthreads();
#pragma unroll
    for (int k = 0; k < BK; ++k) {
      float4 a0 = *(const float4*)&Asm[k][ty * 4];
      float4 a1 = *(const float4*)&Asm[k][ty * 4 + 64];
      float4 b0 = *(const float4*)&Wsm[k][tx * 4];
      float4 b1 = *(const float4*)&Wsm[k][tx * 4 + 64];
      float av[8] = {a0.x, a0.y, a0.z, a0.w, a1.x, a1.y, a1.z, a1.w};
      float bv[8] = {b0.x, b0.y, b0.z, b0.w, b1.x, b1.y, b1.z, b1.w};
#pragma unroll
      for (int i = 0; i < 8; ++i)
#pragma unroll
        for (int j = 0; j < 8; ++j) acc[i][j] += av[i] * bv[j];
    }
  }

#pragma unroll
  for (int ih = 0; ih < 2; ++ih)
#pragma unroll
    for (int i = 0; i < 4; ++i) {
      int m = m0 + ty * 4 + ih * 64 + i;
#pragma unroll
      for (int jh = 0; jh < 2; ++jh) {
        int nn = n0 + tx * 4 + jh * 64;
        if (nn < N) {
          float4 v;
          v.x = acc[ih * 4 + i][jh * 4 + 0] + bias[nn + 0];
          v.y = acc[ih * 4 + i][jh * 4 + 1] + bias[nn + 1];
          v.z = acc[ih * 4 + i][jh * 4 + 2] + bias[nn + 2];
          v.w = acc[ih * 4 + i][jh * 4 + 3] + bias[nn + 3];
          *(float4*)&C[(size_t)m * N + nn] = v;
        }
      }
    }
}

// ---------------------------------------------------------------- MFMA flash rel-attn
// Block: 64 q-rows of one (b,n). Column-strip decomposition: wave owns 16-key
// strip (AC), 16-d strip (PV), w-strips {wave, wave+4} (G). Q/Qr in registers.
// rel_shift (no mask): BD[r][c] = Qr[i0+r+sel].Rext[qmin+w], w = c+63-r,
// sel = (w > wth), wth = T - qmin; Rext rows staged with wrap, Rext[T]=0.
// No-max base-2 softmax (scores bounded ~|2|); li accumulated via ones-MFMA.
#define GT 68

__device__ inline short8 bfrag(const char* base, int lidx, int quad, int kb) {
  return *(const short8*)(base + lidx * 128 + ((((kb << 2) + quad) ^ (lidx & 7)) << 4));
}

__global__ __launch_bounds__(256, 2) void attn_mfma_kernel(
    const ushort* __restrict__ heads, const ushort* __restrict__ rk,
    const ushort* __restrict__ vtg,
    const float* __restrict__ rwb, const float* __restrict__ rrb,
    ushort* __restrict__ avec)
{
  __shared__ __attribute__((aligned(16))) ushort Ks[64 * 64];    // swizzled [key][d]
  __shared__ __attribute__((aligned(16))) ushort Vt[64 * 64];    // swizzled [d][key]
  __shared__ __attribute__((aligned(16))) ushort Re[128 * 64];   // swizzled [w][d]
  __shared__ __attribute__((aligned(16))) ushort Gbt[128 * GT];  // [w][grow]
  __shared__ __attribute__((aligned(16))) ushort Pb[64 * 64];    // swizzled [row][key]

  const int tid  = threadIdx.x;
  const int i0   = blockIdx.x * 64;
  const int b    = blockIdx.y & 1;
  const int n    = blockIdx.y >> 1;
  const int wave = tid >> 6;
  const int lane = tid & 63;
  const int quad = lane >> 4;
  const int lidx = lane & 15;
  const int r8   = lane >> 3;
  const int cs8  = ((lane & 7) ^ (r8 & 7)) * 8;
  const int bn64 = (b * 8 + n) * 64;

  // ---- Q fragments in registers (A-layout: m=lidx within 16-row tile, k=kb*32+quad*8+j)
  short8 qw[4][2], qr[4][2], q4[2];
  {
    auto qfrag = [&](int row, int kb, const float* bias) -> short8 {
      short8 q;
      if (row < T_) q = *(const short8*)&heads[(size_t)(row * 2 + b) * 1536 + n * 64 + kb * 32 + quad * 8];
      else { for (int t = 0; t < 8; ++t) ((ushort*)&q)[t] = 0; }
      short8 o;
#pragma unroll
      for (int t = 0; t < 8; ++t) {
        float f = (bf2f((ushort)((ushort*)&q)[t]) + bias[n * 64 + kb * 32 + quad * 8 + t]) * QSCALE;
        ((ushort*)&o)[t] = f2bf(f);
      }
      return o;
    };
#pragma unroll
    for (int rt = 0; rt < 4; ++rt) {
      int row = i0 + rt * 16 + lidx;
      qw[rt][0] = qfrag(row, 0, rwb); qw[rt][1] = qfrag(row, 1, rwb);
      qr[rt][0] = qfrag(row, 0, rrb); qr[rt][1] = qfrag(row, 1, rrb);
    }
    int row4 = i0 + 64 + lidx;
    q4[0] = qfrag(row4, 0, rrb); q4[1] = qfrag(row4, 1, rrb);
  }

  const int cfix = wave * 16 + lidx;   // this thread's S column

  // loop-invariant gather / P-store addresses (ushort indices)
  int addrG0[16], addrP[16];
#pragma unroll
  for (int rt = 0; rt < 4; ++rt)
#pragma unroll
    for (int reg = 0; reg < 4; ++reg) {
      int rloc = rt * 16 + quad * 4 + reg;
      addrG0[rt * 4 + reg] = (cfix + 63 - rloc) * GT + rloc;
      addrP[rt * 4 + reg]  = rloc * 64 + (((cfix >> 3) ^ (rloc & 7)) * 8) + (cfix & 7);
    }

  float4v oacc[4], liacc[4];
#pragma unroll
  for (int rt = 0; rt < 4; ++rt) {
    oacc[rt]  = (float4v){0.f, 0.f, 0.f, 0.f};
    liacc[rt] = (float4v){0.f, 0.f, 0.f, 0.f};
  }
  short8 ones8;
#pragma unroll
  for (int t = 0; t < 8; ++t) ((ushort*)&ones8)[t] = 0x3F80;   // bf16 1.0

  auto stageKRe = [&](int jt) {
    int j0 = jt * 64, qmin = j0 + 1984 - i0;
#pragma unroll
    for (int half = 0; half < 2; ++half) {
      int r0 = 8 * wave + 32 * half;
      gload16(heads + (size_t)((j0 + r0 + r8) * 2 + b) * 1536 + 512 + n * 64 + cs8, &Ks[r0 * 64]);
    }
#pragma unroll
    for (int q4i = 0; q4i < 4; ++q4i) {
      int r0 = 8 * wave + 32 * q4i;
      int qh = qmin + r0 + r8;
      int p  = (qh > T_) ? (qh - T_ - 1) : ((qh == T_) ? 0 : qh);
      gload16(rk + (size_t)p * 2048 + n * 64 + cs8, &Re[r0 * 64]);
    }
  };
  auto stageV = [&](int jt) {
    int j0 = jt * 64;
#pragma unroll
    for (int half = 0; half < 2; ++half) {
      int r0 = 8 * wave + 32 * half;
      gload16(vtg + (size_t)(bn64 + r0 + r8) * (size_t)T_ + j0 + cs8, &Vt[r0 * 64]);
    }
  };
  auto fixup = [&](int jt) {   // zero Rext[T] row (after DMA drained)
    int qmin = jt * 64 + 1984 - i0;
    int Tidx = T_ - qmin;
    if (Tidx >= 0 && Tidx < 128) {
      if (tid < 32) ((uint*)Re)[Tidx * 32 + tid] = 0u;
      __syncthreads();
    }
  };

  stageKRe(0);
  stageV(0);
  __syncthreads();
  fixup(0);

  for (int jt = 0; jt < 32; ++jt) {
    const int qmin = jt * 64 + 1984 - i0;
    const int wth  = T_ - qmin;   // sel = (w > wth)

    // ---- AC: wave's 16-key column strip, all 4 row-tiles (B-frag reused)
    float4v sv[4];
    {
      const char* KsW = (const char*)Ks + wave * 2048;
      short8 k0 = bfrag(KsW, lidx, quad, 0);
      short8 k1 = bfrag(KsW, lidx, quad, 1);
#pragma unroll
      for (int rt = 0; rt < 4; ++rt) {
        float4v c = {0.f, 0.f, 0.f, 0.f};
        c = __builtin_amdgcn_mfma_f32_16x16x32_bf16(qw[rt][0], k0, c, 0, 0, 0);
        c = __builtin_amdgcn_mfma_f32_16x16x32_bf16(qw[rt][1], k1, c, 0, 0, 0);
        sv[rt] = c;
      }
    }
    // ---- G: strips {wave, wave+4}; C: col->w, row->grow; aligned uint2 stores
#pragma unroll
    for (int si = 0; si < 2; ++si) {
      const int ws = wave + si * 4;
      const int w0 = ws * 16;
      const char* ReW = (const char*)Re + w0 * 128;
      short8 rb0 = bfrag(ReW, lidx, quad, 0);
      short8 rb1 = bfrag(ReW, lidx, quad, 1);
#pragma unroll
      for (int rt = 0; rt < 4; ++rt) {
        bool need = si == 0 ? (rt >= 3 - wave) : (rt <= 3 - wave);
        if (need) {
          float4v g = {0.f, 0.f, 0.f, 0.f};
          g = __builtin_amdgcn_mfma_f32_16x16x32_bf16(qr[rt][0], rb0, g, 0, 0, 0);
          g = __builtin_amdgcn_mfma_f32_16x16x32_bf16(qr[rt][1], rb1, g, 0, 0, 0);
          uint2 st; st.x = pkbf(g[0], g[1]); st.y = pkbf(g[2], g[3]);
          *(uint2*)&Gbt[(w0 + lidx) * GT + rt * 16 + quad * 4] = st;
        }
      }
      if (si == 0 && wth < 63) {   // grow=64 row (for sel at r=63), strips w<64
        float4v g = {0.f, 0.f, 0.f, 0.f};
        g = __builtin_amdgcn_mfma_f32_16x16x32_bf16(q4[0], rb0, g, 0, 0, 0);
        g = __builtin_amdgcn_mfma_f32_16x16x32_bf16(q4[1], rb1, g, 0, 0, 0);
        if (quad == 0) Gbt[(w0 + lidx) * GT + 64] = f2bf(g[0]);
      }
    }
    __syncthreads();   // B1: Gbt ready; Ks/Re consumed; V(jt) DMA drained

    // ---- gather BD + no-max base-2 softmax -> Pb
    {
      const int selb = cfix + 63 - wth;   // sel = (rloc < selb)
#pragma unroll
      for (int rt = 0; rt < 4; ++rt)
#pragma unroll
        for (int reg = 0; reg < 4; ++reg) {
          const int idx = rt * 4 + reg;
          const int rloc = rt * 16 + quad * 4 + reg;
          int ga = addrG0[idx] + ((rloc < selb) ? 1 : 0);
          float x = sv[rt][reg] + bf2f(Gbt[ga]);
          Pb[addrP[idx]] = f2bf(exp2f(x));
        }
    }
    __syncthreads();   // B2: Pb ready

    if (jt < 31) stageKRe(jt + 1);   // DMA overlaps PV; drains at B3

    // ---- PV + li: wave's 16-d strip, all row-tiles (V-frag reused; ones-MFMA li)
    {
      const char* VtW = (const char*)Vt + wave * 2048;
      short8 vb0 = bfrag(VtW, lidx, quad, 0);
      short8 vb1 = bfrag(VtW, lidx, quad, 1);
#pragma unroll
      for (int rt = 0; rt < 4; ++rt) {
        const char* PbW = (const char*)Pb + rt * 2048;
        short8 pa0 = bfrag(PbW, lidx, quad, 0);
        short8 pa1 = bfrag(PbW, lidx, quad, 1);
        oacc[rt]  = __builtin_amdgcn_mfma_f32_16x16x32_bf16(pa0, vb0, oacc[rt], 0, 0, 0);
        oacc[rt]  = __builtin_amdgcn_mfma_f32_16x16x32_bf16(pa1, vb1, oacc[rt], 0, 0, 0);
        liacc[rt] = __builtin_amdgcn_mfma_f32_16x16x32_bf16(pa0, ones8, liacc[rt], 0, 0, 0);
        liacc[rt] = __builtin_amdgcn_mfma_f32_16x16x32_bf16(pa1, ones8, liacc[rt], 0, 0, 0);
      }
    }
    __syncthreads();   // B3: Pb/Vt consumed; KRe(jt+1) DMA drained

    if (jt < 31) {
      stageV(jt + 1);   // DMA overlaps next AC/G; drains at next B1
      fixup(jt + 1);
    }
  }

  // ---- epilogue: O[row][d=wave*16+lidx] / li[row]
#pragma unroll
  for (int rt = 0; rt < 4; ++rt)
#pragma unroll
    for (int reg = 0; reg < 4; ++reg) {
      int i = i0 + rt * 16 + quad * 4 + reg;
      float val = oacc[rt][reg] / liacc[rt][reg];
      avec[(size_t)(i * 2 + b) * DM + n * 64 + wave * 16 + lidx] = f2bf(val);
    }
}

// ---------------------------------------------------------------- LN(residual), dual out
__global__ __launch_bounds__(256) void ln_res_kernel(
    float* __restrict__ h, ushort* __restrict__ hb, const float* __restrict__ delta,
    const float* __restrict__ s, const float* __restrict__ bb)
{
  const int m = blockIdx.x;
  const int tid = threadIdx.x;
  float* hp = h + (size_t)m * DM;
  ushort* hbp = hb + (size_t)m * DM;
  const float* dp = delta + (size_t)m * DM;
  float x0 = hp[tid] + dp[tid];
  float x1 = hp[tid + 256] + dp[tid + 256];
  float sum = x0 + x1, sq = x0 * x0 + x1 * x1;
#pragma unroll
  for (int o = 32; o > 0; o >>= 1) { sum += __shfl_down(sum, o); sq += __shfl_down(sq, o); }
  __shared__ float part[8];
  int wv = tid >> 6;
  if ((tid & 63) == 0) { part[wv * 2] = sum; part[wv * 2 + 1] = sq; }
  __syncthreads();
  float ts = part[0] + part[2] + part[4] + part[6];
  float tq = part[1] + part[3] + part[5] + part[7];
  float mu = ts * (1.f / DM);
  float var = tq * (1.f / DM) - mu * mu;
  float rs = rsqrtf(var + 1e-5f);
  float y0 = (x0 - mu) * rs * s[tid]       + bb[tid];
  float y1 = (x1 - mu) * rs * s[tid + 256] + bb[tid + 256];
  hp[tid] = y0;       hbp[tid] = f2bf(y0);
  hp[tid + 256] = y1; hbp[tid + 256] = f2bf(y1);
}

// ---------------------------------------------------------------- classifier reorder
__global__ __launch_bounds__(256) void reorder_kernel(const float* __restrict__ ct,
                                                      float* __restrict__ out) {
  int idx = blockIdx.x * 256 + threadIdx.x;
  if (idx >= B_ * NCLS * T_) return;
  int t  = idx & (T_ - 1);
  int nc = (idx >> 11) & 63;
  int bb = idx >> 17;
  out[idx] = ct[(size_t)(t * B_ + bb) * NCLS + nc];
}

// ---------------------------------------------------------------- launch
extern "C" void kernel_launch(void* const* d_in, const int* in_sizes, int n_in,
                              void* d_out, int out_size, void* d_ws, size_t ws_size,
                              hipStream_t stream)
{
  const float* x     = (const float*)d_in[0];
  const float* emb_w = (const float*)d_in[1];
  const float* emb_b = (const float*)d_in[2];
  const float* rwb   = (const float*)d_in[3];
  const float* rrb   = (const float*)d_in[4];
  const float* qkv_w = (const float*)d_in[5];
  const float* qkv_b = (const float*)d_in[6];
  const float* rproj = (const float*)d_in[7];
  const float* o_w   = (const float*)d_in[8];
  const float* ln1s  = (const float*)d_in[9];
  const float* ln1b  = (const float*)d_in[10];
  const float* ff1w  = (const float*)d_in[11];
  const float* ff1b  = (const float*)d_in[12];
  const float* ff2w  = (const float*)d_in[13];
  const float* ff2b  = (const float*)d_in[14];
  const float* ln2s  = (const float*)d_in[15];
  const float* ln2b  = (const float*)d_in[16];
  const float* clsw  = (const float*)d_in[17];
  const float* clsb  = (const float*)d_in[18];
  float* out = (float*)d_out;

  char* p = (char*)d_ws;
  float*  h       = (float*)p;   p += (size_t)MT * DM * 4;
  float*  tmpf    = (float*)p;   p += (size_t)MT * DM * 4;
  ushort* hb      = (ushort*)p;  p += (size_t)MT * DM * 2;
  ushort* headsb  = (ushort*)p;  p += (size_t)MT * 1536 * 2;
  ushort* peb     = (ushort*)p;  p += (size_t)T_ * DM * 2;
  ushort* rk_all  = (ushort*)p;  p += (size_t)T_ * 2048 * 2;
  ushort* avecb   = (ushort*)p;  p += (size_t)MT * DM * 2;
  ushort* xfb     = (ushort*)p;  p += (size_t)MT * INCH * 2;
  ushort* emb_wb  = (ushort*)p;  p += (size_t)DM * INCH * 2;
  ushort* qkv_wb  = (ushort*)p;  p += (size_t)4 * 1536 * DM * 2;
  ushort* rproj_wb= (ushort*)p;  p += (size_t)4 * DM * DM * 2;
  ushort* o_wb    = (ushort*)p;  p += (size_t)4 * DM * DM * 2;
  ushort* ff1_wb  = (ushort*)p;  p += (size_t)4 * DI * DM * 2;
  ushort* ff2_wb  = (ushort*)p;  p += (size_t)4 * DM * DI * 2;
  ushort* vtg     = xfb;   // region reused; live only vtrans->attn

  cvt6_kernel<<<dim3(4096, 6), 256, 0, stream>>>(
      emb_w, emb_wb, DM * INCH / 4,
      qkv_w, qkv_wb, 4 * 1536 * DM / 4,
      rproj, rproj_wb, 4 * DM * DM / 4,
      o_w,   o_wb,   4 * DM * DM / 4,
      ff1w,  ff1_wb, 4 * DI * DM / 4,
      ff2w,  ff2_wb, 4 * DM * DI / 4);
  pos_kernel<<<(T_ * DM) / 256, 256, 0, stream>>>(peb);
  xpose_kernel<<<dim3(T_ / 32, INCH / 32, B_), 256, 0, stream>>>(x, xfb);

  gemm_bf16<64, 2, false><<<dim3(DM / 128, MT / 64), 256, 0, stream>>>(
      xfb, emb_wb, emb_b, h, hb, MT, DM, INCH);
  gemm_bf16<128, 1, false><<<dim3(2048 / 128, T_ / 128), 256, 0, stream>>>(
      peb, rproj_wb, nullptr, nullptr, rk_all, T_, 2048, DM);

  for (int l = 0; l < 4; ++l) {
    gemm_bf16<128, 1, false><<<dim3(1536 / 128, MT / 128), 256, 0, stream>>>(
        hb, qkv_wb + (size_t)l * 1536 * DM, qkv_b + l * 1536, nullptr, headsb, MT, 1536, DM);
    vtrans_kernel<<<dim3(T_ / 64, B_ * NH), 256, 0, stream>>>(headsb, vtg);
    attn_mfma_kernel<<<dim3(T_ / 64, B_ * NH), 256, 0, stream>>>(
        headsb, rk_all + (size_t)l * 512, vtg, rwb, rrb, avecb);
    gemm_bf16<32, 0, false><<<dim3(DM / 128, MT / 32), 256, 0, stream>>>(
        avecb, o_wb + (size_t)l * DM * DM, nullptr, tmpf, nullptr, MT, DM, DM);
    ln_res_kernel<<<MT, 256, 0, stream>>>(h, hb, tmpf, ln1s + l * DM, ln1b + l * DM);
    gemm_bf16<128, 1, true><<<dim3(DI / 128, MT / 128), 256, 0, stream>>>(
        hb, ff1_wb + (size_t)l * DI * DM, ff1b + l * DI, nullptr, xfb, MT, DI, DM);
    gemm_bf16<32, 0, false><<<dim3(DM / 128, MT / 32), 256, 0, stream>>>(
        xfb, ff2_wb + (size_t)l * DM * DI, ff2b + l * DM, tmpf, nullptr, MT, DM, DI);
    ln_res_kernel<<<MT, 256, 0, stream>>>(h, hb, tmpf, ln2s + l * DM, ln2b + l * DM);
  }

  gemm_f32<<<dim3(1, MT / BM), 256, 0, stream>>>(h, clsw, clsb, tmpf, MT, NCLS, DM);
  reorder_kernel<<<(B_ * NCLS * T_) / 256, 256, 0, stream>>>(tmpf, out);
}